// Round 15
// baseline (336.662 us; speedup 1.0000x reference)
//
#include <hip/hip_runtime.h>

// ---------------- helpers ----------------

__device__ __forceinline__ float bcast(float v, int l) {
    return __int_as_float(__builtin_amdgcn_readlane(__float_as_int(v), l));
}

#define REPD(M,P,B) \
 M(0,P,B)  M(1,P,B)  M(2,P,B)  M(3,P,B)  M(4,P,B)  M(5,P,B)  M(6,P,B)  M(7,P,B) \
 M(8,P,B)  M(9,P,B)  M(10,P,B) M(11,P,B) M(12,P,B) M(13,P,B) M(14,P,B) M(15,P,B) \
 M(16,P,B) M(17,P,B) M(18,P,B) M(19,P,B) M(20,P,B) M(21,P,B) M(22,P,B) M(23,P,B) \
 M(24,P,B) M(25,P,B) M(26,P,B) M(27,P,B) M(28,P,B) M(29,P,B) M(30,P,B) M(31,P,B) \
 M(32,P,B) M(33,P,B) M(34,P,B) M(35,P,B) M(36,P,B) M(37,P,B) M(38,P,B) M(39,P,B) \
 M(40,P,B) M(41,P,B) M(42,P,B) M(43,P,B) M(44,P,B) M(45,P,B) M(46,P,B) M(47,P,B) \
 M(48,P,B) M(49,P,B) M(50,P,B) M(51,P,B) M(52,P,B) M(53,P,B) M(54,P,B) M(55,P,B) \
 M(56,P,B) M(57,P,B) M(58,P,B) M(59,P,B) M(60,P,B) M(61,P,B) M(62,P,B) M(63,P,B)

#define WLOAD(J,P,B) float P##J = (B)[(J)*64+lane];

#define REPP(M,P,X,S0,S1) \
 M(0,1,P,X,S0,S1)  M(2,3,P,X,S0,S1)  M(4,5,P,X,S0,S1)  M(6,7,P,X,S0,S1) \
 M(8,9,P,X,S0,S1)  M(10,11,P,X,S0,S1) M(12,13,P,X,S0,S1) M(14,15,P,X,S0,S1) \
 M(16,17,P,X,S0,S1) M(18,19,P,X,S0,S1) M(20,21,P,X,S0,S1) M(22,23,P,X,S0,S1) \
 M(24,25,P,X,S0,S1) M(26,27,P,X,S0,S1) M(28,29,P,X,S0,S1) M(30,31,P,X,S0,S1) \
 M(32,33,P,X,S0,S1) M(34,35,P,X,S0,S1) M(36,37,P,X,S0,S1) M(38,39,P,X,S0,S1) \
 M(40,41,P,X,S0,S1) M(42,43,P,X,S0,S1) M(44,45,P,X,S0,S1) M(46,47,P,X,S0,S1) \
 M(48,49,P,X,S0,S1) M(50,51,P,X,S0,S1) M(52,53,P,X,S0,S1) M(54,55,P,X,S0,S1) \
 M(56,57,P,X,S0,S1) M(58,59,P,X,S0,S1) M(60,61,P,X,S0,S1) M(62,63,P,X,S0,S1)

#define WFMA(J,K,P,X,S0,S1) \
 S0 = fmaf(bcast(X,J), P##J, S0); \
 S1 = fmaf(bcast(X,K), P##K, S1);

// ---------------- MFMA split-bf16 machinery ----------------

typedef short bf16x8 __attribute__((ext_vector_type(8)));
typedef float f32x4  __attribute__((ext_vector_type(4)));

__device__ __forceinline__ unsigned short f2bf_rne(float x) {
    unsigned u = __float_as_uint(x);
    unsigned r = u + 0x7FFFu + ((u >> 16) & 1u);
    return (unsigned short)(r >> 16);
}

__device__ __forceinline__ void a_frag(const float* __restrict__ row, int kt, int g4,
                                       bf16x8& ah, bf16x8& al)
{
    const float4 a0 = *(const float4*)(row + kt*32 + g4);
    const float4 a1 = *(const float4*)(row + kt*32 + 16 + g4);
    float v0 = a0.x, v1 = a0.y, v2 = a0.z, v3 = a0.w;
    float v4 = a1.x, v5 = a1.y, v6 = a1.z, v7 = a1.w;
#define CVT1(idx, val) { \
    unsigned short hh = f2bf_rne(val); \
    float lf = (val) - __uint_as_float((unsigned)hh << 16); \
    ah[idx] = (short)hh; al[idx] = (short)f2bf_rne(lf); }
    CVT1(0,v0) CVT1(1,v1) CVT1(2,v2) CVT1(3,v3)
    CVT1(4,v4) CVT1(5,v5) CVT1(6,v6) CVT1(7,v7)
#undef CVT1
}

__device__ __forceinline__ void mm64(const bf16x8& ah0, const bf16x8& al0,
                                     const bf16x8& ah1, const bf16x8& al1,
                                     const unsigned short* __restrict__ pW,
                                     int lane, f32x4 acc[4])
{
#pragma unroll
    for (int nt = 0; nt < 4; ++nt) {
        f32x4 a = {0.f, 0.f, 0.f, 0.f};
#pragma unroll
        for (int kt = 0; kt < 2; ++kt) {
            bf16x8 bh = *(const bf16x8*)(pW + (kt*4+nt)*1024 + lane*8);
            bf16x8 bl = *(const bf16x8*)(pW + (kt*4+nt)*1024 + 512 + lane*8);
            bf16x8 aH = kt ? ah1 : ah0;
            bf16x8 aL = kt ? al1 : al0;
            a = __builtin_amdgcn_mfma_f32_16x16x32_bf16(aH, bh, a, 0, 0, 0);
            a = __builtin_amdgcn_mfma_f32_16x16x32_bf16(aL, bh, a, 0, 0, 0);
            a = __builtin_amdgcn_mfma_f32_16x16x32_bf16(aH, bl, a, 0, 0, 0);
        }
        acc[nt] = a;
    }
}

// ================= prep: packB (blocks 0..6) + bhist (blocks 7..1542) ============
// NOTE: cnt* MUST be zeroed by the preceding k_zero3 launch — no zeroing here
// (a same-kernel zero block would race with the hist blocks; caused the r14 fault).

#define BKT 512
#define EPT 8
#define EPB (BKT*EPT)

__global__ __launch_bounds__(256) void k_prep(
    const float* W0, unsigned short* d0, const float* W1, unsigned short* d1,
    const float* W2, unsigned short* d2, const float* W3, unsigned short* d3,
    const float* W4, unsigned short* d4, const float* W5, unsigned short* d5,
    const float* W6, unsigned short* d6,
    int* cnt0, int nb0, int* cnt1, int nb1, int* cntL, int nbL,
    const int2* __restrict__ e0, int E0,
    const int2* __restrict__ e1, int E1,
    const int* __restrict__ lab, int NN)
{
    int b = blockIdx.x;
    if (b < 7) {
        const float* W; unsigned short* dst;
        switch (b) {
            case 0: W=W0; dst=d0; break;
            case 1: W=W1; dst=d1; break;
            case 2: W=W2; dst=d2; break;
            case 3: W=W3; dst=d3; break;
            case 4: W=W4; dst=d4; break;
            case 5: W=W5; dst=d5; break;
            default: W=W6; dst=d6; break;
        }
        int t = threadIdx.x;
        for (int slot = t; slot < 512; slot += 256) {
            int frag = slot >> 6;
            int lane = slot & 63;
            int kt = frag >> 2, nt = frag & 3;
            int g4 = (lane >> 4) * 4, n = nt*16 + (lane & 15);
            for (int j = 0; j < 8; ++j) {
                int k = kt*32 + (j>>2)*16 + g4 + (j&3);
                float x = W[k*64 + n];
                unsigned short hh = f2bf_rne(x);
                float lf = x - __uint_as_float((unsigned)hh << 16);
                dst[frag*1024 + 0*512 + lane*8 + j] = hh;
                dst[frag*1024 + 1*512 + lane*8 + j] = f2bf_rne(lf);
            }
        }
        return;
    }
    {
        const int2* e = nullptr; const int* lv = nullptr; int* gcnt; int total; int nb;
        int bloc, nblocks;
        int bb = b - 7;
        if (bb < 1024)      { e = e0; gcnt = cnt0; total = E0; nb = nb0; bloc = bb;        nblocks = 1024; }
        else if (bb < 1280) { e = e1; gcnt = cnt1; total = E1; nb = nb1; bloc = bb - 1024; nblocks = 256; }
        else                { lv = lab; gcnt = cntL; total = NN; nb = nbL; bloc = bb - 1280; nblocks = 256; }
        __shared__ int c[400];
        for (int i = threadIdx.x; i < nb; i += 256) c[i] = 0;
        __syncthreads();
        for (int idx = bloc*256 + threadIdx.x; idx < total; idx += nblocks*256)
            atomicAdd(&c[(lv ? lv[idx] : e[idx].y) >> 8], 1);
        __syncthreads();
        for (int i = threadIdx.x; i < nb; i += 256) if (c[i]) atomicAdd(&gcnt[i], c[i]);
    }
}

__global__ __launch_bounds__(256) void k_zero3(
    int* c0, int n0, int* c1, int n1, int* c2, int n2)
{
    int t = threadIdx.x;
    for (int i = t; i < n0; i += 256) c0[i] = 0;
    for (int i = t; i < n1; i += 256) c1[i] = 0;
    for (int i = t; i < n2; i += 256) c2[i] = 0;
}

__global__ __launch_bounds__(512) void k_bscan3(
    const int* c0, int* b0, int* u0, int nb0, int t0,
    const int* c1, int* b1, int* u1, int nb1, int t1,
    const int* c2, int* b2, int* u2, int nb2, int t2)
{
    const int* cnt; int* base; int* cur; int nb; int tot;
    if (blockIdx.x == 0) { cnt=c0; base=b0; cur=u0; nb=nb0; tot=t0; }
    else if (blockIdx.x == 1) { cnt=c1; base=b1; cur=u1; nb=nb1; tot=t1; }
    else { cnt=c2; base=b2; cur=u2; nb=nb2; tot=t2; }
    __shared__ int sc[512];
    int t = threadIdx.x;
    int v = (t < nb) ? cnt[t] : 0;
    sc[t] = v; __syncthreads();
    for (int o = 1; o < 512; o <<= 1) {
        int a = (t >= o) ? sc[t-o] : 0;
        __syncthreads();
        sc[t] += a;
        __syncthreads();
    }
    if (t < nb) { int ex = sc[t] - v; base[t] = ex; cur[t] = ex; }
    if (t == nb) base[nb] = tot;
}

__global__ __launch_bounds__(BKT) void k_bucket3(
    const int2* __restrict__ e0, int* cur0, int2* eb0, int E0, int nb0, int GB0,
    const int2* __restrict__ e1, int* cur1, int2* eb1, int E1, int nb1, int GB1,
    const int* __restrict__ lab, int* curL, int2* ebL, int NN, int nbL)
{
    const int2* e = nullptr; const int* lv = nullptr; int* cur; int2* ebuf;
    int total; int nb; int bloc;
    int b = blockIdx.x;
    if (b < GB0)            { e = e0; cur = cur0; ebuf = eb0; total = E0; nb = nb0; bloc = b; }
    else if (b < GB0 + GB1) { e = e1; cur = cur1; ebuf = eb1; total = E1; nb = nb1; bloc = b - GB0; }
    else                    { lv = lab; cur = curL; ebuf = ebL; total = NN; nb = nbL; bloc = b - GB0 - GB1; }
    __shared__ int cnt[400];
    __shared__ int chunk[400];
    int t = threadIdx.x;
    int base = bloc * EPB;
    for (int i = t; i < nb; i += BKT) cnt[i] = 0;
    __syncthreads();
    int2 ed[EPT]; int rk[EPT];
#pragma unroll
    for (int k = 0; k < EPT; ++k) {
        int idx = base + k*BKT + t;
        if (idx < total) {
            ed[k] = lv ? make_int2(idx, lv[idx]) : e[idx];
            rk[k] = atomicAdd(&cnt[ed[k].y >> 8], 1);
        } else rk[k] = -1;
    }
    __syncthreads();
    for (int i = t; i < nb; i += BKT) { int c = cnt[i]; if (c) chunk[i] = atomicAdd(&cur[i], c); }
    __syncthreads();
#pragma unroll
    for (int k = 0; k < EPT; ++k)
        if (rk[k] >= 0) ebuf[chunk[ed[k].y >> 8] + rk[k]] = ed[k];
}

__global__ __launch_bounds__(512) void k_final3(
    const int2* eb0, const int* base0, int* rs0, int* srcs0, int nd0, int et0, int NB0_,
    const int2* eb1, const int* base1, int* rs1, int* srcs1, int nd1, int et1, int NB1_,
    const int2* ebL, const int* baseL, int* rsL, int* srcsL, int ndL, int etL, int NBL_)
{
    const int2* ebuf; const int* base_; int* rs; int* srcs; int ndst; int etot; int nb; int bloc;
    int b = blockIdx.x;
    if (b < NB0_)              { ebuf=eb0; base_=base0; rs=rs0; srcs=srcs0; ndst=nd0; etot=et0; nb=NB0_; bloc=b; }
    else if (b < NB0_ + NB1_)  { ebuf=eb1; base_=base1; rs=rs1; srcs=srcs1; ndst=nd1; etot=et1; nb=NB1_; bloc=b-NB0_; }
    else                       { ebuf=ebL; base_=baseL; rs=rsL; srcs=srcsL; ndst=ndL; etot=etL; nb=NBL_; bloc=b-NB0_-NB1_; }
    __shared__ int h[256];
    __shared__ int sc[256];
    int t = threadIdx.x;
    int base = base_[bloc];
    int cnt  = base_[bloc+1] - base;
    int d0 = bloc << 8;
    if (t < 256) h[t] = 0;
    __syncthreads();
    for (int i = t; i < cnt; i += 512) atomicAdd(&h[ebuf[base+i].y - d0], 1);
    __syncthreads();
    int v = (t < 256) ? h[t] : 0;
    if (t < 256) sc[t] = v;
    __syncthreads();
    for (int o = 1; o < 256; o <<= 1) {
        int a = (t < 256 && t >= o) ? sc[t-o] : 0;
        __syncthreads();
        if (t < 256) sc[t] += a;
        __syncthreads();
    }
    if (t < 256) {
        int gpos = base + sc[t] - v;
        if (d0 + t < ndst) rs[d0+t] = gpos;
        h[t] = gpos;
    }
    if (bloc == nb-1 && t == 0) rs[ndst] = etot;
    __syncthreads();
    for (int i = t; i < cnt; i += 512) {
        int2 ed = ebuf[base+i];
        int pos = atomicAdd(&h[ed.y - d0], 1);
        srcs[pos] = ed.x;
    }
}

// ================= fused MFMA compute kernels =================

__global__ __launch_bounds__(256) void k_feat_pre0_g(
    const float* __restrict__ feat, const float* __restrict__ pts,
    const float* __restrict__ ctr, const int* __restrict__ lab,
    const float* __restrict__ Wfe, const float* __restrict__ bfe,
    const float* __restrict__ Wh, const float* __restrict__ bh,
    const unsigned short* __restrict__ pWf0, const float* __restrict__ Wf0h,
    const float* __restrict__ bf0,
    float* __restrict__ rel, float* __restrict__ x1,
    float* __restrict__ p, float* __restrict__ q, int ntiles)
{
    __shared__ float xp[4][16*68];
    __shared__ float dd[4][64];
    int lane = threadIdx.x & 63;
    int w = threadIdx.x >> 6;
    int tile = blockIdx.x*4 + w;
    if (tile >= ntiles) return;
    int r0 = tile*16;
    int row = lane & 15;
    int cg  = lane >> 4;
    int r = r0 + row;
    int l = lab[r];
    float pr0 = pts[r*3+0], pr1 = pts[r*3+1], pr2 = pts[r*3+2];
    float rv0 = pr0 - ctr[l*3+0], rv1 = pr1 - ctr[l*3+1], rv2 = pr2 - ctr[l*3+2];
    if (cg == 0) { rel[r*3+0]=rv0; rel[r*3+1]=rv1; rel[r*3+2]=rv2; }
    float f0 = feat[r*4+0], f1 = feat[r*4+1], f2 = feat[r*4+2], f3 = feat[r*4+3];
#pragma unroll
    for (int k = 0; k < 16; ++k) {
        int c = cg*16 + k;
        float v = bfe[c];
        v = fmaf(f0, Wfe[0*64+c], v);
        v = fmaf(f1, Wfe[1*64+c], v);
        v = fmaf(f2, Wfe[2*64+c], v);
        v = fmaf(f3, Wfe[3*64+c], v);
        v = fmaf(rv0, Wfe[4*64+c], v);
        v = fmaf(rv1, Wfe[5*64+c], v);
        v = fmaf(rv2, Wfe[6*64+c], v);
        xp[w][row*68 + c] = fmaxf(v, 0.f);
    }
    {
        int j = cg < 3 ? cg : 2;
        float accd = 0.f;
#pragma unroll 16
        for (int k2 = 0; k2 < 64; ++k2)
            accd = fmaf(xp[w][row*68 + k2], Wh[k2*3 + j], accd);
        dd[w][row*4 + cg] = tanhf(accd + bh[j]);
    }
    int g4 = cg * 4;
    const float* lrow = &xp[w][row*68];
    bf16x8 ah0, al0, ah1, al1;
    a_frag(lrow, 0, g4, ah0, al0);
    a_frag(lrow, 1, g4, ah1, al1);
    f32x4 acc[4];
    mm64(ah0, al0, ah1, al1, pWf0, lane, acc);
    int rloc = cg*4;
#pragma unroll
    for (int nt = 0; nt < 4; ++nt) {
        int c = nt*16 + row;
        float w0t = Wf0h[0*64+c], w1t = Wf0h[1*64+c], w2t = Wf0h[2*64+c];
        float bfc = bf0[c];
#pragma unroll
        for (int reg = 0; reg < 4; ++reg) {
            int rr = r0 + rloc + reg;
            int rl = rloc + reg;
            float pp0 = pts[rr*3+0], pp1 = pts[rr*3+1], pp2 = pts[rr*3+2];
            float v = acc[nt][reg] + pp0*w0t + pp1*w1t + pp2*w2t;
            p[(size_t)rr*64 + c] = v;
            x1[(size_t)rr*64 + c] = xp[w][rl*68 + c];
            float d0 = dd[w][rl*4+0], d1 = dd[w][rl*4+1], d2 = dd[w][rl*4+2];
            q[(size_t)rr*64 + c] = (d0-pp0)*w0t + (d1-pp1)*w1t + (d2-pp2)*w2t + bfc;
        }
    }
}

__global__ __launch_bounds__(256) void k_post_m2l_g(
    const float* __restrict__ agg, const unsigned short* __restrict__ pWg,
    const float* __restrict__ bg, const float* __restrict__ x1,
    const unsigned short* __restrict__ pWm, const float* __restrict__ bm,
    const float* __restrict__ Wmt, const float* __restrict__ rel,
    float* __restrict__ x2, float* __restrict__ h, int ntiles)
{
    __shared__ float xp[4][16*68];
    int lane = threadIdx.x & 63;
    int w = threadIdx.x >> 6;
    int tile = blockIdx.x*4 + w;
    if (tile >= ntiles) return;
    int r0 = tile*16;
    int g4 = (lane >> 4) * 4;
    int rloc = (lane >> 4) * 4;
    const float* rowp = agg + (size_t)(r0 + (lane & 15)) * 64;
    bf16x8 ah0, al0, ah1, al1;
    a_frag(rowp, 0, g4, ah0, al0);
    a_frag(rowp, 1, g4, ah1, al1);
    f32x4 acc[4];
    mm64(ah0, al0, ah1, al1, pWg, lane, acc);
#pragma unroll
    for (int nt = 0; nt < 4; ++nt) {
        int c = nt*16 + (lane & 15);
        float bc = bg[c];
#pragma unroll
        for (int reg = 0; reg < 4; ++reg) {
            int r = r0 + rloc + reg;
            float v = fmaxf(acc[nt][reg] + bc, 0.f) + x1[(size_t)r*64 + c];
            x2[(size_t)r*64 + c] = v;
            xp[w][(rloc+reg)*68 + c] = v;
        }
    }
    const float* lrow = &xp[w][(lane & 15)*68];
    a_frag(lrow, 0, g4, ah0, al0);
    a_frag(lrow, 1, g4, ah1, al1);
    mm64(ah0, al0, ah1, al1, pWm, lane, acc);
#pragma unroll
    for (int nt = 0; nt < 4; ++nt) {
        int c = nt*16 + (lane & 15);
        float bc = bm[c];
        float w0t = Wmt[0*64+c], w1t = Wmt[1*64+c], w2t = Wmt[2*64+c];
#pragma unroll
        for (int reg = 0; reg < 4; ++reg) {
            int r = r0 + rloc + reg;
            float v = acc[nt][reg] + bc + rel[r*3+0]*w0t + rel[r*3+1]*w1t + rel[r*3+2]*w2t;
            h[(size_t)r*64 + c] = fmaxf(v, 0.f);
        }
    }
}

__global__ __launch_bounds__(256) void k_l2m_pre2_g(
    const float* __restrict__ c4, const int* __restrict__ lab,
    const unsigned short* __restrict__ pWl, const float* __restrict__ bl,
    const float* __restrict__ Wlt, const float* __restrict__ rel,
    const unsigned short* __restrict__ pWf2, const float* __restrict__ Wf2t,
    const float* __restrict__ pts,
    const float* __restrict__ Wh, const float* __restrict__ bh,
    const float* __restrict__ bf,
    float* __restrict__ x5, float* __restrict__ p, float* __restrict__ q, int ntiles)
{
    __shared__ float xp[4][16*68];
    __shared__ float dd[4][64];
    int lane = threadIdx.x & 63;
    int w = threadIdx.x >> 6;
    int tile = blockIdx.x*4 + w;
    if (tile >= ntiles) return;
    int r0 = tile*16;
    int g4 = (lane >> 4) * 4;
    int rloc = (lane >> 4) * 4;
    int rA = r0 + (lane & 15);
    const float* rowp = c4 + (size_t)lab[rA] * 64;
    bf16x8 ah0, al0, ah1, al1;
    a_frag(rowp, 0, g4, ah0, al0);
    a_frag(rowp, 1, g4, ah1, al1);
    f32x4 acc[4];
    mm64(ah0, al0, ah1, al1, pWl, lane, acc);
#pragma unroll
    for (int nt = 0; nt < 4; ++nt) {
        int c = nt*16 + (lane & 15);
        float bc = bl[c];
        float w0t = Wlt[0*64+c], w1t = Wlt[1*64+c], w2t = Wlt[2*64+c];
#pragma unroll
        for (int reg = 0; reg < 4; ++reg) {
            int r = r0 + rloc + reg;
            float v = acc[nt][reg] + bc + rel[r*3+0]*w0t + rel[r*3+1]*w1t + rel[r*3+2]*w2t;
            v = fmaxf(v, 0.f);
            x5[(size_t)r*64 + c] = v;
            xp[w][(rloc+reg)*68 + c] = v;
        }
    }
    {
        int rowl = lane & 15;
        int jj = lane >> 4;
        int j = jj < 3 ? jj : 2;
        float accd = 0.f;
#pragma unroll 16
        for (int k = 0; k < 64; ++k)
            accd = fmaf(xp[w][rowl*68 + k], Wh[k*3 + j], accd);
        dd[w][rowl*4 + jj] = tanhf(accd + bh[j]);
    }
    const float* lrow = &xp[w][(lane & 15)*68];
    a_frag(lrow, 0, g4, ah0, al0);
    a_frag(lrow, 1, g4, ah1, al1);
    mm64(ah0, al0, ah1, al1, pWf2, lane, acc);
#pragma unroll
    for (int nt = 0; nt < 4; ++nt) {
        int c = nt*16 + (lane & 15);
        float w0t = Wf2t[0*64+c], w1t = Wf2t[1*64+c], w2t = Wf2t[2*64+c];
        float bfc = bf[c];
#pragma unroll
        for (int reg = 0; reg < 4; ++reg) {
            int r = r0 + rloc + reg;
            int rl = rloc + reg;
            float p0 = pts[r*3+0], p1 = pts[r*3+1], p2 = pts[r*3+2];
            float v = acc[nt][reg] + p0*w0t + p1*w1t + p2*w2t;
            p[(size_t)r*64 + c] = v;
            float d0 = dd[w][rl*4+0], d1 = dd[w][rl*4+1], d2 = dd[w][rl*4+2];
            q[(size_t)r*64 + c] = (d0-p0)*w0t + (d1-p1)*w1t + (d2-p2)*w2t + bfc;
        }
    }
}

__global__ __launch_bounds__(256) void k_gemm_final(
    const float* __restrict__ agg, const unsigned short* __restrict__ pWg2,
    const float* __restrict__ bg2,
    const float* __restrict__ x5, const float* __restrict__ x2,
    const unsigned short* __restrict__ pW1, const float* __restrict__ b1,
    const float* __restrict__ W2, const float* __restrict__ b2,
    float* __restrict__ out, int ntiles)
{
    __shared__ float xp[4][16*68];
    int lane = threadIdx.x & 63;
    int w = threadIdx.x >> 6;
    int tile = blockIdx.x*4 + w;
    if (tile >= ntiles) return;
    int r0 = tile*16;
    int g4 = (lane >> 4) * 4;
    int rloc = (lane >> 4) * 4;
    const float* rowp = agg + (size_t)(r0 + (lane & 15)) * 64;
    bf16x8 ah0, al0, ah1, al1;
    a_frag(rowp, 0, g4, ah0, al0);
    a_frag(rowp, 1, g4, ah1, al1);
    f32x4 acc[4];
    mm64(ah0, al0, ah1, al1, pWg2, lane, acc);
#pragma unroll
    for (int nt = 0; nt < 4; ++nt) {
        int c = nt*16 + (lane & 15);
        float bc = bg2[c];
#pragma unroll
        for (int reg = 0; reg < 4; ++reg) {
            int r = r0 + rloc + reg;
            float v = fmaxf(acc[nt][reg] + bc, 0.f)
                    + x5[(size_t)r*64 + c] + x2[(size_t)r*64 + c];
            xp[w][(rloc+reg)*68 + c] = v;
        }
    }
    const float* lrow = &xp[w][(lane & 15)*68];
    a_frag(lrow, 0, g4, ah0, al0);
    a_frag(lrow, 1, g4, ah1, al1);
    mm64(ah0, al0, ah1, al1, pW1, lane, acc);
    float part0[4] = {0.f,0.f,0.f,0.f};
    float part1[4] = {0.f,0.f,0.f,0.f};
    float part2[4] = {0.f,0.f,0.f,0.f};
    float part3[4] = {0.f,0.f,0.f,0.f};
#pragma unroll
    for (int nt = 0; nt < 4; ++nt) {
        int c = nt*16 + (lane & 15);
        float bc = b1[c];
        float4 w2v = *(const float4*)(W2 + c*4);
#pragma unroll
        for (int reg = 0; reg < 4; ++reg) {
            float t = fmaxf(acc[nt][reg] + bc, 0.f);
            part0[reg] = fmaf(t, w2v.x, part0[reg]);
            part1[reg] = fmaf(t, w2v.y, part1[reg]);
            part2[reg] = fmaf(t, w2v.z, part2[reg]);
            part3[reg] = fmaf(t, w2v.w, part3[reg]);
        }
    }
#pragma unroll
    for (int m = 1; m < 16; m <<= 1) {
#pragma unroll
        for (int reg = 0; reg < 4; ++reg) {
            part0[reg] += __shfl_xor(part0[reg], m);
            part1[reg] += __shfl_xor(part1[reg], m);
            part2[reg] += __shfl_xor(part2[reg], m);
            part3[reg] += __shfl_xor(part3[reg], m);
        }
    }
    if ((lane & 15) == 0) {
        float b20 = b2[0], b21 = b2[1], b22 = b2[2], b23 = b2[3];
#pragma unroll
        for (int reg = 0; reg < 4; ++reg) {
            int r = r0 + rloc + reg;
            *(float4*)(out + (size_t)r*4) =
                make_float4(part0[reg]+b20, part1[reg]+b21, part2[reg]+b22, part3[reg]+b23);
        }
    }
}

// ================= segmax (float2-wide) + M-sized VALU kernels =================

// 1 dest/wave; lane halves cover 2 srcs per instruction (512 B); 8 float2 accs.
__global__ __launch_bounds__(256) void k_seg_max_gnn(
    const int* __restrict__ rs, const int* __restrict__ srcs,
    const float* __restrict__ p, float* __restrict__ q, int n)
{
    int lane = threadIdx.x & 63;
    int half = lane >> 5;
    int cl   = lane & 31;
    int wid  = blockIdx.x * (blockDim.x >> 6) + (threadIdx.x >> 6);
    int nw   = gridDim.x * (blockDim.x >> 6);
    const float2* p2 = (const float2*)p;
    for (int d = wid; d < n; d += nw) {
        int du = __builtin_amdgcn_readfirstlane(d);
        int beg = rs[du], end = rs[du+1];
        float ax[8], ay[8];
#pragma unroll
        for (int u = 0; u < 8; ++u) { ax[u] = -1e30f; ay[u] = -1e30f; }
        int c = beg;
        while (c + 16 <= end) {
            int s[8];
#pragma unroll
            for (int u = 0; u < 8; ++u) s[u] = srcs[c + 2*u + half];
#pragma unroll
            for (int u = 0; u < 8; ++u) {
                float2 v = p2[(size_t)s[u]*32 + cl];
                ax[u] = fmaxf(ax[u], v.x);
                ay[u] = fmaxf(ay[u], v.y);
            }
            c += 16;
        }
        while (c + 8 <= end) {
            int s0 = srcs[c + half],     s1 = srcs[c + 2 + half];
            int s2 = srcs[c + 4 + half], s3 = srcs[c + 6 + half];
            float2 v0 = p2[(size_t)s0*32 + cl];
            float2 v1 = p2[(size_t)s1*32 + cl];
            float2 v2 = p2[(size_t)s2*32 + cl];
            float2 v3 = p2[(size_t)s3*32 + cl];
            ax[0] = fmaxf(ax[0], v0.x); ay[0] = fmaxf(ay[0], v0.y);
            ax[1] = fmaxf(ax[1], v1.x); ay[1] = fmaxf(ay[1], v1.y);
            ax[2] = fmaxf(ax[2], v2.x); ay[2] = fmaxf(ay[2], v2.y);
            ax[3] = fmaxf(ax[3], v3.x); ay[3] = fmaxf(ay[3], v3.y);
            c += 8;
        }
        while (c + 2 <= end) {
            int s0 = srcs[c + half];
            float2 v = p2[(size_t)s0*32 + cl];
            ax[0] = fmaxf(ax[0], v.x);
            ay[0] = fmaxf(ay[0], v.y);
            c += 2;
        }
        if (c < end) {
            int s0 = srcs[c];
            float2 v = p2[(size_t)s0*32 + cl];
            ax[0] = fmaxf(ax[0], v.x);
            ay[0] = fmaxf(ay[0], v.y);
        }
        float mx = fmaxf(fmaxf(fmaxf(ax[0],ax[1]), fmaxf(ax[2],ax[3])),
                         fmaxf(fmaxf(ax[4],ax[5]), fmaxf(ax[6],ax[7])));
        float my = fmaxf(fmaxf(fmaxf(ay[0],ay[1]), fmaxf(ay[2],ay[3])),
                         fmaxf(fmaxf(ay[4],ay[5]), fmaxf(ay[6],ay[7])));
        mx = fmaxf(mx, __shfl_xor(mx, 32));
        my = fmaxf(my, __shfl_xor(my, 32));
        if (half == 0) {
            float2* q2 = (float2*)q;
            size_t o = (size_t)du*32 + cl;
            float2 qv = q2[o];
            q2[o] = make_float2(fmaxf(mx + qv.x, 0.f), fmaxf(my + qv.y, 0.f));
        }
    }
}

__global__ __launch_bounds__(256, 2) void k_seglab_pre1(
    const int* __restrict__ rsL, const int* __restrict__ srcsL,
    const float* __restrict__ h, const float* __restrict__ pos,
    const float* __restrict__ Wh, const float* __restrict__ bh,
    const float* __restrict__ Wf, const float* __restrict__ bf,
    float* __restrict__ c, float* __restrict__ pa, float* __restrict__ qa, int m)
{
    int lane = threadIdx.x & 63;
    int wid  = blockIdx.x * (blockDim.x >> 6) + (threadIdx.x >> 6);
    int nw   = gridDim.x * (blockDim.x >> 6);
    REPD(WLOAD, wc, Wf + 3*64)
    float w0 = Wf[0*64+lane], w1 = Wf[1*64+lane], w2 = Wf[2*64+lane];
    float bfl = bf[lane];
    float wh0 = Wh[lane*3+0], wh1 = Wh[lane*3+1], wh2 = Wh[lane*3+2];
    float bh0 = bh[0], bh1 = bh[1], bh2 = bh[2];
    for (int d0 = wid*2; d0 < m; d0 += nw*2) {
        int dA = __builtin_amdgcn_readfirstlane(d0);
        int dB = dA + 1;
        int begA = rsL[dA], endA = rsL[dA+1], endB = rsL[dA+2];
        int ca = begA, cb = endA;
        float aA0=-1e30f, aA1=-1e30f, aB0=-1e30f, aB1=-1e30f;
        while (ca+2 <= endA && cb+2 <= endB) {
            int s0=srcsL[ca], s1=srcsL[ca+1], s2=srcsL[cb], s3=srcsL[cb+1];
            aA0 = fmaxf(aA0, h[(size_t)s0*64+lane]);
            aA1 = fmaxf(aA1, h[(size_t)s1*64+lane]);
            aB0 = fmaxf(aB0, h[(size_t)s2*64+lane]);
            aB1 = fmaxf(aB1, h[(size_t)s3*64+lane]);
            ca += 2; cb += 2;
        }
        while (ca+2 <= endA) {
            int s0=srcsL[ca], s1=srcsL[ca+1];
            aA0 = fmaxf(aA0, h[(size_t)s0*64+lane]);
            aA1 = fmaxf(aA1, h[(size_t)s1*64+lane]);
            ca += 2;
        }
        while (cb+2 <= endB) {
            int s2=srcsL[cb], s3=srcsL[cb+1];
            aB0 = fmaxf(aB0, h[(size_t)s2*64+lane]);
            aB1 = fmaxf(aB1, h[(size_t)s3*64+lane]);
            cb += 2;
        }
        if (ca < endA) aA0 = fmaxf(aA0, h[(size_t)srcsL[ca]*64+lane]);
        if (cb < endB) aB0 = fmaxf(aB0, h[(size_t)srcsL[cb]*64+lane]);
        float cvA = fmaxf(fmaxf(aA0,aA1), 0.f);
        float cvB = fmaxf(fmaxf(aB0,aB1), 0.f);
        c[(size_t)dA*64+lane] = cvA;
        c[(size_t)dB*64+lane] = cvB;
        float d0A = cvA*wh0, d1A = cvA*wh1, d2A = cvA*wh2;
        float d0B = cvB*wh0, d1B = cvB*wh1, d2B = cvB*wh2;
#pragma unroll
        for (int o = 32; o; o >>= 1) {
            d0A += __shfl_xor(d0A,o); d1A += __shfl_xor(d1A,o); d2A += __shfl_xor(d2A,o);
            d0B += __shfl_xor(d0B,o); d1B += __shfl_xor(d1B,o); d2B += __shfl_xor(d2B,o);
        }
        d0A = tanhf(d0A+bh0); d1A = tanhf(d1A+bh1); d2A = tanhf(d2A+bh2);
        d0B = tanhf(d0B+bh0); d1B = tanhf(d1B+bh1); d2B = tanhf(d2B+bh2);
        float pA0 = pos[dA*3+0], pA1 = pos[dA*3+1], pA2 = pos[dA*3+2];
        float pB0 = pos[dB*3+0], pB1 = pos[dB*3+1], pB2 = pos[dB*3+2];
        float s0A=0.f, s1A=0.f, s0B=0.f, s1B=0.f;
        REPP(WFMA, wc, cvA, s0A, s1A)
        REPP(WFMA, wc, cvB, s0B, s1B)
        pa[(size_t)dA*64+lane] = s0A+s1A + pA0*w0 + pA1*w1 + pA2*w2;
        pa[(size_t)dB*64+lane] = s0B+s1B + pB0*w0 + pB1*w1 + pB2*w2;
        qa[(size_t)dA*64+lane] = (d0A-pA0)*w0 + (d1A-pA1)*w1 + (d2A-pA2)*w2 + bfl;
        qa[(size_t)dB*64+lane] = (d0B-pB0)*w0 + (d1B-pB1)*w1 + (d2B-pB2)*w2 + bfl;
    }
}

__global__ __launch_bounds__(256, 2) void k_gnn_post(
    const float* __restrict__ agg, const float* __restrict__ Wg,
    const float* __restrict__ bg, const float* __restrict__ xres,
    float* __restrict__ out, int n)
{
    int lane = threadIdx.x & 63;
    int wid  = blockIdx.x * (blockDim.x >> 6) + (threadIdx.x >> 6);
    int nw   = gridDim.x * (blockDim.x >> 6);
    REPD(WLOAD, wg, Wg)
    float bgl = bg[lane];
    for (int i0 = wid*2; i0 < n; i0 += nw*2) {
        int iA = __builtin_amdgcn_readfirstlane(i0);
        size_t oA = (size_t)iA*64 + lane, oB = oA + 64;
        float avA = agg[oA], avB = agg[oB];
        float s0A=0.f, s1A=0.f, s0B=0.f, s1B=0.f;
        REPP(WFMA, wg, avA, s0A, s1A)
        REPP(WFMA, wg, avB, s0B, s1B)
        out[oA] = fmaxf(s0A+s1A + bgl, 0.f) + xres[oA];
        out[oB] = fmaxf(s0B+s1B + bgl, 0.f) + xres[oB];
    }
}

// ---------------- launch ----------------

extern "C" void kernel_launch(void* const* d_in, const int* in_sizes, int n_in,
                              void* d_out, int out_size, void* d_ws, size_t ws_size,
                              hipStream_t stream)
{
    const int N = 100000, M = 10000, E0 = 1600000, E1 = 320000;
    const int NB0 = (N + 255) / 256;
    const int NB1 = (M + 255) / 256;
    const int NBL = (M + 255) / 256;
    const int GB0 = (E0 + EPB - 1) / EPB;
    const int GB1 = (E1 + EPB - 1) / EPB;
    const int GBL = (N + EPB - 1) / EPB;

    const float* feat = (const float*)d_in[0];
    const float* pts  = (const float*)d_in[1];
    const float* ctr  = (const float*)d_in[2];
    const int*   lab  = (const int*)d_in[3];
    const int2*  e0   = (const int2*)d_in[4];
    const int2*  e1   = (const int2*)d_in[5];
    const float* feW  = (const float*)d_in[6];
    const float* feb  = (const float*)d_in[7];
    const float* Wh   = (const float*)d_in[8];
    const float* bh   = (const float*)d_in[9];
    const float* Wf   = (const float*)d_in[10];
    const float* bf   = (const float*)d_in[11];
    const float* Wg   = (const float*)d_in[12];
    const float* bg   = (const float*)d_in[13];
    const float* m2lW = (const float*)d_in[14];
    const float* m2lb = (const float*)d_in[15];
    const float* l2mW = (const float*)d_in[16];
    const float* l2mb = (const float*)d_in[17];
    const float* cW1  = (const float*)d_in[18];
    const float* cb1  = (const float*)d_in[19];
    const float* cW2  = (const float*)d_in[20];
    const float* cb2  = (const float*)d_in[21];
    float* out = (float*)d_out;

    char* ws = (char*)d_ws;
    size_t off = 0;
    auto alloc = [&](size_t bytes) -> char* {
        char* r = ws + off; off += (bytes + 255) & ~(size_t)255; return r;
    };
    float* rel   = (float*)alloc((size_t)N*3*4);
    float* x1    = (float*)alloc((size_t)N*64*4);
    float* x2    = (float*)alloc((size_t)N*64*4);   // hosts ebufs pre-compute
    float* p     = (float*)alloc((size_t)N*64*4);
    float* q     = (float*)alloc((size_t)N*64*4);
    float* c     = (float*)alloc((size_t)M*64*4);
    float* c4    = (float*)alloc((size_t)M*64*4);
    int* rs0     = (int*)alloc((size_t)(N+2)*4);
    int* srcs0   = (int*)alloc((size_t)E0*4);
    int* rs1     = (int*)alloc((size_t)(M+2)*4);
    int* srcs1   = (int*)alloc((size_t)E1*4);
    int* rsL     = (int*)alloc((size_t)(M+2)*4);
    int* srcsL   = (int*)alloc((size_t)N*4);
    int* cnt0    = (int*)alloc((size_t)NB0*4);
    int* cnt1    = (int*)alloc((size_t)NB1*4);
    int* cntL    = (int*)alloc((size_t)NBL*4);
    int* base0   = (int*)alloc((size_t)(NB0+1)*4);
    int* base1   = (int*)alloc((size_t)(NB1+1)*4);
    int* baseL   = (int*)alloc((size_t)(NBL+1)*4);
    int* cur0    = (int*)alloc((size_t)NB0*4);
    int* cur1    = (int*)alloc((size_t)NB1*4);
    int* curL    = (int*)alloc((size_t)NBL*4);
    unsigned short* pWf0  = (unsigned short*)alloc(8192*2);
    unsigned short* pWg0  = (unsigned short*)alloc(8192*2);
    unsigned short* pWm   = (unsigned short*)alloc(8192*2);
    unsigned short* pWl2m = (unsigned short*)alloc(8192*2);
    unsigned short* pWf2  = (unsigned short*)alloc(8192*2);
    unsigned short* pWg2  = (unsigned short*)alloc(8192*2);
    unsigned short* pW1   = (unsigned short*)alloc(8192*2);
    (void)ws_size; (void)in_sizes; (void)n_in; (void)out_size;

    int2* ebuf0 = (int2*)x2;
    int2* ebuf1 = ebuf0 + E0;
    int2* ebufL = ebuf1 + E1;

    dim3 blk(256);
    const int gridM = 640, gSeg = 2048;
    const int NT = N / 16;
    const int gG = (NT + 3) / 4;

    // ---- zero (separate launch: MUST complete before k_prep's hist atomics) ----
    k_zero3<<<1, blk, 0, stream>>>(cnt0, NB0, cnt1, NB1, cntL, NBL);
    // ---- merged pack (7 blocks) + hist (1536 blocks) ----
    k_prep<<<7 + 1536, blk, 0, stream>>>(
        Wf + 0*67*64 + 3*64, pWf0,
        Wg + 0*64*64,        pWg0,
        m2lW,                pWm,
        l2mW,                pWl2m,
        Wf + 2*67*64 + 3*64, pWf2,
        Wg + 2*64*64,        pWg2,
        cW1,                 pW1,
        cnt0, NB0, cnt1, NB1, cntL, NBL,
        e0, E0, e1, E1, lab, N);
    k_bscan3<<<3, 512, 0, stream>>>(cnt0, base0, cur0, NB0, E0,
                                    cnt1, base1, cur1, NB1, E1,
                                    cntL, baseL, curL, NBL, N);
    k_bucket3<<<GB0 + GB1 + GBL, BKT, 0, stream>>>(
        e0, cur0, ebuf0, E0, NB0, GB0,
        e1, cur1, ebuf1, E1, NB1, GB1,
        lab, curL, ebufL, N, NBL);
    k_final3<<<NB0 + NB1 + NBL, 512, 0, stream>>>(
        ebuf0, base0, rs0, srcs0, N, E0, NB0,
        ebuf1, base1, rs1, srcs1, M, E1, NB1,
        ebufL, baseL, rsL, srcsL, M, N, NBL);

    // ---- layer 0 ----
    k_feat_pre0_g<<<gG, blk, 0, stream>>>(feat, pts, ctr, lab, feW, feb,
                                          Wh+0*64*3, bh+0*3,
                                          pWf0, Wf+0*67*64, bf+0*64,
                                          rel, x1, p, q, NT);
    k_seg_max_gnn<<<gSeg, blk, 0, stream>>>(rs0, srcs0, p, q, N);
    k_post_m2l_g<<<gG, blk, 0, stream>>>(q, pWg0, bg+0*64, x1,
                                         pWm, m2lb, m2lW+64*64, rel,
                                         x2, p, NT);

    // ---- layer 1 (clusters, VALU) ----
    float* p1 = q;
    float* q1 = q + (size_t)M*64;
    k_seglab_pre1<<<gridM, blk, 0, stream>>>(rsL, srcsL, p, ctr,
                                             Wh+1*64*3, bh+1*3, Wf+1*67*64, bf+1*64,
                                             c, p1, q1, M);
    k_seg_max_gnn<<<640, blk, 0, stream>>>(rs1, srcs1, p1, q1, M);
    k_gnn_post<<<gridM, blk, 0, stream>>>(q1, Wg+1*64*64, bg+1*64, c, c4, M);

    // ---- l2m (+q fold) + layer 2 + classifier ----
    k_l2m_pre2_g<<<gG, blk, 0, stream>>>(c4, lab, pWl2m, l2mb, l2mW+64*64, rel,
                                         pWf2, Wf+2*67*64, pts,
                                         Wh+2*64*3, bh+2*3, bf+2*64,
                                         x1, p, q, NT);                     // x5 -> x1
    k_seg_max_gnn<<<gSeg, blk, 0, stream>>>(rs0, srcs0, p, q, N);
    k_gemm_final<<<gG, blk, 0, stream>>>(q, pWg2, bg+2*64, x1, x2,
                                         pW1, cb1, cW2, cb2, out, NT);
}

// Round 16
// 295.021 us; speedup vs baseline: 1.1411x; 1.1411x over previous
//
#include <hip/hip_runtime.h>
#include <hip/hip_fp16.h>

// ---------------- helpers ----------------

__device__ __forceinline__ float bcast(float v, int l) {
    return __int_as_float(__builtin_amdgcn_readlane(__float_as_int(v), l));
}

#define REPD(M,P,B) \
 M(0,P,B)  M(1,P,B)  M(2,P,B)  M(3,P,B)  M(4,P,B)  M(5,P,B)  M(6,P,B)  M(7,P,B) \
 M(8,P,B)  M(9,P,B)  M(10,P,B) M(11,P,B) M(12,P,B) M(13,P,B) M(14,P,B) M(15,P,B) \
 M(16,P,B) M(17,P,B) M(18,P,B) M(19,P,B) M(20,P,B) M(21,P,B) M(22,P,B) M(23,P,B) \
 M(24,P,B) M(25,P,B) M(26,P,B) M(27,P,B) M(28,P,B) M(29,P,B) M(30,P,B) M(31,P,B) \
 M(32,P,B) M(33,P,B) M(34,P,B) M(35,P,B) M(36,P,B) M(37,P,B) M(38,P,B) M(39,P,B) \
 M(40,P,B) M(41,P,B) M(42,P,B) M(43,P,B) M(44,P,B) M(45,P,B) M(46,P,B) M(47,P,B) \
 M(48,P,B) M(49,P,B) M(50,P,B) M(51,P,B) M(52,P,B) M(53,P,B) M(54,P,B) M(55,P,B) \
 M(56,P,B) M(57,P,B) M(58,P,B) M(59,P,B) M(60,P,B) M(61,P,B) M(62,P,B) M(63,P,B)

#define WLOAD(J,P,B) float P##J = (B)[(J)*64+lane];

#define REPP(M,P,X,S0,S1) \
 M(0,1,P,X,S0,S1)  M(2,3,P,X,S0,S1)  M(4,5,P,X,S0,S1)  M(6,7,P,X,S0,S1) \
 M(8,9,P,X,S0,S1)  M(10,11,P,X,S0,S1) M(12,13,P,X,S0,S1) M(14,15,P,X,S0,S1) \
 M(16,17,P,X,S0,S1) M(18,19,P,X,S0,S1) M(20,21,P,X,S0,S1) M(22,23,P,X,S0,S1) \
 M(24,25,P,X,S0,S1) M(26,27,P,X,S0,S1) M(28,29,P,X,S0,S1) M(30,31,P,X,S0,S1) \
 M(32,33,P,X,S0,S1) M(34,35,P,X,S0,S1) M(36,37,P,X,S0,S1) M(38,39,P,X,S0,S1) \
 M(40,41,P,X,S0,S1) M(42,43,P,X,S0,S1) M(44,45,P,X,S0,S1) M(46,47,P,X,S0,S1) \
 M(48,49,P,X,S0,S1) M(50,51,P,X,S0,S1) M(52,53,P,X,S0,S1) M(54,55,P,X,S0,S1) \
 M(56,57,P,X,S0,S1) M(58,59,P,X,S0,S1) M(60,61,P,X,S0,S1) M(62,63,P,X,S0,S1)

#define WFMA(J,K,P,X,S0,S1) \
 S0 = fmaf(bcast(X,J), P##J, S0); \
 S1 = fmaf(bcast(X,K), P##K, S1);

// ---------------- MFMA split-bf16 machinery ----------------

typedef short bf16x8 __attribute__((ext_vector_type(8)));
typedef float f32x4  __attribute__((ext_vector_type(4)));

__device__ __forceinline__ unsigned short f2bf_rne(float x) {
    unsigned u = __float_as_uint(x);
    unsigned r = u + 0x7FFFu + ((u >> 16) & 1u);
    return (unsigned short)(r >> 16);
}

__device__ __forceinline__ void a_frag(const float* __restrict__ row, int kt, int g4,
                                       bf16x8& ah, bf16x8& al)
{
    const float4 a0 = *(const float4*)(row + kt*32 + g4);
    const float4 a1 = *(const float4*)(row + kt*32 + 16 + g4);
    float v0 = a0.x, v1 = a0.y, v2 = a0.z, v3 = a0.w;
    float v4 = a1.x, v5 = a1.y, v6 = a1.z, v7 = a1.w;
#define CVT1(idx, val) { \
    unsigned short hh = f2bf_rne(val); \
    float lf = (val) - __uint_as_float((unsigned)hh << 16); \
    ah[idx] = (short)hh; al[idx] = (short)f2bf_rne(lf); }
    CVT1(0,v0) CVT1(1,v1) CVT1(2,v2) CVT1(3,v3)
    CVT1(4,v4) CVT1(5,v5) CVT1(6,v6) CVT1(7,v7)
#undef CVT1
}

__device__ __forceinline__ void mm64(const bf16x8& ah0, const bf16x8& al0,
                                     const bf16x8& ah1, const bf16x8& al1,
                                     const unsigned short* __restrict__ pW,
                                     int lane, f32x4 acc[4])
{
#pragma unroll
    for (int nt = 0; nt < 4; ++nt) {
        f32x4 a = {0.f, 0.f, 0.f, 0.f};
#pragma unroll
        for (int kt = 0; kt < 2; ++kt) {
            bf16x8 bh = *(const bf16x8*)(pW + (kt*4+nt)*1024 + lane*8);
            bf16x8 bl = *(const bf16x8*)(pW + (kt*4+nt)*1024 + 512 + lane*8);
            bf16x8 aH = kt ? ah1 : ah0;
            bf16x8 aL = kt ? al1 : al0;
            a = __builtin_amdgcn_mfma_f32_16x16x32_bf16(aH, bh, a, 0, 0, 0);
            a = __builtin_amdgcn_mfma_f32_16x16x32_bf16(aL, bh, a, 0, 0, 0);
            a = __builtin_amdgcn_mfma_f32_16x16x32_bf16(aH, bl, a, 0, 0, 0);
        }
        acc[nt] = a;
    }
}

// ================= prep: packB (blocks 0..6) + bhist (blocks 7..1542) ============
// cnt* MUST be zeroed by the preceding k_zero3 launch (r14 lesson: no same-kernel zero).

#define BKT 512
#define EPT 8
#define EPB (BKT*EPT)

__global__ __launch_bounds__(256) void k_prep(
    const float* W0, unsigned short* d0, const float* W1, unsigned short* d1,
    const float* W2, unsigned short* d2, const float* W3, unsigned short* d3,
    const float* W4, unsigned short* d4, const float* W5, unsigned short* d5,
    const float* W6, unsigned short* d6,
    int* cnt0, int nb0, int* cnt1, int nb1, int* cntL, int nbL,
    const int2* __restrict__ e0, int E0,
    const int2* __restrict__ e1, int E1,
    const int* __restrict__ lab, int NN)
{
    int b = blockIdx.x;
    if (b < 7) {
        const float* W; unsigned short* dst;
        switch (b) {
            case 0: W=W0; dst=d0; break;
            case 1: W=W1; dst=d1; break;
            case 2: W=W2; dst=d2; break;
            case 3: W=W3; dst=d3; break;
            case 4: W=W4; dst=d4; break;
            case 5: W=W5; dst=d5; break;
            default: W=W6; dst=d6; break;
        }
        int t = threadIdx.x;
        for (int slot = t; slot < 512; slot += 256) {
            int frag = slot >> 6;
            int lane = slot & 63;
            int kt = frag >> 2, nt = frag & 3;
            int g4 = (lane >> 4) * 4, n = nt*16 + (lane & 15);
            for (int j = 0; j < 8; ++j) {
                int k = kt*32 + (j>>2)*16 + g4 + (j&3);
                float x = W[k*64 + n];
                unsigned short hh = f2bf_rne(x);
                float lf = x - __uint_as_float((unsigned)hh << 16);
                dst[frag*1024 + 0*512 + lane*8 + j] = hh;
                dst[frag*1024 + 1*512 + lane*8 + j] = f2bf_rne(lf);
            }
        }
        return;
    }
    {
        const int2* e = nullptr; const int* lv = nullptr; int* gcnt; int total; int nb;
        int bloc, nblocks;
        int bb = b - 7;
        if (bb < 1024)      { e = e0; gcnt = cnt0; total = E0; nb = nb0; bloc = bb;        nblocks = 1024; }
        else if (bb < 1280) { e = e1; gcnt = cnt1; total = E1; nb = nb1; bloc = bb - 1024; nblocks = 256; }
        else                { lv = lab; gcnt = cntL; total = NN; nb = nbL; bloc = bb - 1280; nblocks = 256; }
        __shared__ int c[400];
        for (int i = threadIdx.x; i < nb; i += 256) c[i] = 0;
        __syncthreads();
        for (int idx = bloc*256 + threadIdx.x; idx < total; idx += nblocks*256)
            atomicAdd(&c[(lv ? lv[idx] : e[idx].y) >> 8], 1);
        __syncthreads();
        for (int i = threadIdx.x; i < nb; i += 256) if (c[i]) atomicAdd(&gcnt[i], c[i]);
    }
}

__global__ __launch_bounds__(256) void k_zero3(
    int* c0, int n0, int* c1, int n1, int* c2, int n2)
{
    int t = threadIdx.x;
    for (int i = t; i < n0; i += 256) c0[i] = 0;
    for (int i = t; i < n1; i += 256) c1[i] = 0;
    for (int i = t; i < n2; i += 256) c2[i] = 0;
}

__global__ __launch_bounds__(512) void k_bscan3(
    const int* c0, int* b0, int* u0, int nb0, int t0,
    const int* c1, int* b1, int* u1, int nb1, int t1,
    const int* c2, int* b2, int* u2, int nb2, int t2)
{
    const int* cnt; int* base; int* cur; int nb; int tot;
    if (blockIdx.x == 0) { cnt=c0; base=b0; cur=u0; nb=nb0; tot=t0; }
    else if (blockIdx.x == 1) { cnt=c1; base=b1; cur=u1; nb=nb1; tot=t1; }
    else { cnt=c2; base=b2; cur=u2; nb=nb2; tot=t2; }
    __shared__ int sc[512];
    int t = threadIdx.x;
    int v = (t < nb) ? cnt[t] : 0;
    sc[t] = v; __syncthreads();
    for (int o = 1; o < 512; o <<= 1) {
        int a = (t >= o) ? sc[t-o] : 0;
        __syncthreads();
        sc[t] += a;
        __syncthreads();
    }
    if (t < nb) { int ex = sc[t] - v; base[t] = ex; cur[t] = ex; }
    if (t == nb) base[nb] = tot;
}

__global__ __launch_bounds__(BKT) void k_bucket3(
    const int2* __restrict__ e0, int* cur0, int2* eb0, int E0, int nb0, int GB0,
    const int2* __restrict__ e1, int* cur1, int2* eb1, int E1, int nb1, int GB1,
    const int* __restrict__ lab, int* curL, int2* ebL, int NN, int nbL)
{
    const int2* e = nullptr; const int* lv = nullptr; int* cur; int2* ebuf;
    int total; int nb; int bloc;
    int b = blockIdx.x;
    if (b < GB0)            { e = e0; cur = cur0; ebuf = eb0; total = E0; nb = nb0; bloc = b; }
    else if (b < GB0 + GB1) { e = e1; cur = cur1; ebuf = eb1; total = E1; nb = nb1; bloc = b - GB0; }
    else                    { lv = lab; cur = curL; ebuf = ebL; total = NN; nb = nbL; bloc = b - GB0 - GB1; }
    __shared__ int cnt[400];
    __shared__ int chunk[400];
    int t = threadIdx.x;
    int base = bloc * EPB;
    for (int i = t; i < nb; i += BKT) cnt[i] = 0;
    __syncthreads();
    int2 ed[EPT]; int rk[EPT];
#pragma unroll
    for (int k = 0; k < EPT; ++k) {
        int idx = base + k*BKT + t;
        if (idx < total) {
            ed[k] = lv ? make_int2(idx, lv[idx]) : e[idx];
            rk[k] = atomicAdd(&cnt[ed[k].y >> 8], 1);
        } else rk[k] = -1;
    }
    __syncthreads();
    for (int i = t; i < nb; i += BKT) { int c = cnt[i]; if (c) chunk[i] = atomicAdd(&cur[i], c); }
    __syncthreads();
#pragma unroll
    for (int k = 0; k < EPT; ++k)
        if (rk[k] >= 0) ebuf[chunk[ed[k].y >> 8] + rk[k]] = ed[k];
}

__global__ __launch_bounds__(512) void k_final3(
    const int2* eb0, const int* base0, int* rs0, int* srcs0, int nd0, int et0, int NB0_,
    const int2* eb1, const int* base1, int* rs1, int* srcs1, int nd1, int et1, int NB1_,
    const int2* ebL, const int* baseL, int* rsL, int* srcsL, int ndL, int etL, int NBL_)
{
    const int2* ebuf; const int* base_; int* rs; int* srcs; int ndst; int etot; int nb; int bloc;
    int b = blockIdx.x;
    if (b < NB0_)              { ebuf=eb0; base_=base0; rs=rs0; srcs=srcs0; ndst=nd0; etot=et0; nb=NB0_; bloc=b; }
    else if (b < NB0_ + NB1_)  { ebuf=eb1; base_=base1; rs=rs1; srcs=srcs1; ndst=nd1; etot=et1; nb=NB1_; bloc=b-NB0_; }
    else                       { ebuf=ebL; base_=baseL; rs=rsL; srcs=srcsL; ndst=ndL; etot=etL; nb=NBL_; bloc=b-NB0_-NB1_; }
    __shared__ int h[256];
    __shared__ int sc[256];
    int t = threadIdx.x;
    int base = base_[bloc];
    int cnt  = base_[bloc+1] - base;
    int d0 = bloc << 8;
    if (t < 256) h[t] = 0;
    __syncthreads();
    for (int i = t; i < cnt; i += 512) atomicAdd(&h[ebuf[base+i].y - d0], 1);
    __syncthreads();
    int v = (t < 256) ? h[t] : 0;
    if (t < 256) sc[t] = v;
    __syncthreads();
    for (int o = 1; o < 256; o <<= 1) {
        int a = (t < 256 && t >= o) ? sc[t-o] : 0;
        __syncthreads();
        if (t < 256) sc[t] += a;
        __syncthreads();
    }
    if (t < 256) {
        int gpos = base + sc[t] - v;
        if (d0 + t < ndst) rs[d0+t] = gpos;
        h[t] = gpos;
    }
    if (bloc == nb-1 && t == 0) rs[ndst] = etot;
    __syncthreads();
    for (int i = t; i < cnt; i += 512) {
        int2 ed = ebuf[base+i];
        int pos = atomicAdd(&h[ed.y - d0], 1);
        srcs[pos] = ed.x;
    }
}

// ================= fused MFMA compute kernels =================

__global__ __launch_bounds__(256) void k_feat_pre0_g(
    const float* __restrict__ feat, const float* __restrict__ pts,
    const float* __restrict__ ctr, const int* __restrict__ lab,
    const float* __restrict__ Wfe, const float* __restrict__ bfe,
    const float* __restrict__ Wh, const float* __restrict__ bh,
    const unsigned short* __restrict__ pWf0, const float* __restrict__ Wf0h,
    const float* __restrict__ bf0,
    float* __restrict__ rel, float* __restrict__ x1,
    __half* __restrict__ p16, float* __restrict__ q, int ntiles)
{
    __shared__ float xp[4][16*68];
    __shared__ float dd[4][64];
    int lane = threadIdx.x & 63;
    int w = threadIdx.x >> 6;
    int tile = blockIdx.x*4 + w;
    if (tile >= ntiles) return;
    int r0 = tile*16;
    int row = lane & 15;
    int cg  = lane >> 4;
    int r = r0 + row;
    int l = lab[r];
    float pr0 = pts[r*3+0], pr1 = pts[r*3+1], pr2 = pts[r*3+2];
    float rv0 = pr0 - ctr[l*3+0], rv1 = pr1 - ctr[l*3+1], rv2 = pr2 - ctr[l*3+2];
    if (cg == 0) { rel[r*3+0]=rv0; rel[r*3+1]=rv1; rel[r*3+2]=rv2; }
    float f0 = feat[r*4+0], f1 = feat[r*4+1], f2 = feat[r*4+2], f3 = feat[r*4+3];
#pragma unroll
    for (int k = 0; k < 16; ++k) {
        int c = cg*16 + k;
        float v = bfe[c];
        v = fmaf(f0, Wfe[0*64+c], v);
        v = fmaf(f1, Wfe[1*64+c], v);
        v = fmaf(f2, Wfe[2*64+c], v);
        v = fmaf(f3, Wfe[3*64+c], v);
        v = fmaf(rv0, Wfe[4*64+c], v);
        v = fmaf(rv1, Wfe[5*64+c], v);
        v = fmaf(rv2, Wfe[6*64+c], v);
        xp[w][row*68 + c] = fmaxf(v, 0.f);
    }
    {
        int j = cg < 3 ? cg : 2;
        float accd = 0.f;
#pragma unroll 16
        for (int k2 = 0; k2 < 64; ++k2)
            accd = fmaf(xp[w][row*68 + k2], Wh[k2*3 + j], accd);
        dd[w][row*4 + cg] = tanhf(accd + bh[j]);
    }
    int g4 = cg * 4;
    const float* lrow = &xp[w][row*68];
    bf16x8 ah0, al0, ah1, al1;
    a_frag(lrow, 0, g4, ah0, al0);
    a_frag(lrow, 1, g4, ah1, al1);
    f32x4 acc[4];
    mm64(ah0, al0, ah1, al1, pWf0, lane, acc);
    int rloc = cg*4;
#pragma unroll
    for (int nt = 0; nt < 4; ++nt) {
        int c = nt*16 + row;
        float w0t = Wf0h[0*64+c], w1t = Wf0h[1*64+c], w2t = Wf0h[2*64+c];
        float bfc = bf0[c];
#pragma unroll
        for (int reg = 0; reg < 4; ++reg) {
            int rr = r0 + rloc + reg;
            int rl = rloc + reg;
            float pp0 = pts[rr*3+0], pp1 = pts[rr*3+1], pp2 = pts[rr*3+2];
            float v = acc[nt][reg] + pp0*w0t + pp1*w1t + pp2*w2t;
            p16[(size_t)rr*64 + c] = __float2half(v);
            x1[(size_t)rr*64 + c] = xp[w][rl*68 + c];
            float d0 = dd[w][rl*4+0], d1 = dd[w][rl*4+1], d2 = dd[w][rl*4+2];
            q[(size_t)rr*64 + c] = (d0-pp0)*w0t + (d1-pp1)*w1t + (d2-pp2)*w2t + bfc;
        }
    }
}

__global__ __launch_bounds__(256) void k_post_m2l_g(
    const float* __restrict__ agg, const unsigned short* __restrict__ pWg,
    const float* __restrict__ bg, const float* __restrict__ x1,
    const unsigned short* __restrict__ pWm, const float* __restrict__ bm,
    const float* __restrict__ Wmt, const float* __restrict__ rel,
    float* __restrict__ x2, float* __restrict__ h, int ntiles)
{
    __shared__ float xp[4][16*68];
    int lane = threadIdx.x & 63;
    int w = threadIdx.x >> 6;
    int tile = blockIdx.x*4 + w;
    if (tile >= ntiles) return;
    int r0 = tile*16;
    int g4 = (lane >> 4) * 4;
    int rloc = (lane >> 4) * 4;
    const float* rowp = agg + (size_t)(r0 + (lane & 15)) * 64;
    bf16x8 ah0, al0, ah1, al1;
    a_frag(rowp, 0, g4, ah0, al0);
    a_frag(rowp, 1, g4, ah1, al1);
    f32x4 acc[4];
    mm64(ah0, al0, ah1, al1, pWg, lane, acc);
#pragma unroll
    for (int nt = 0; nt < 4; ++nt) {
        int c = nt*16 + (lane & 15);
        float bc = bg[c];
#pragma unroll
        for (int reg = 0; reg < 4; ++reg) {
            int r = r0 + rloc + reg;
            float v = fmaxf(acc[nt][reg] + bc, 0.f) + x1[(size_t)r*64 + c];
            x2[(size_t)r*64 + c] = v;
            xp[w][(rloc+reg)*68 + c] = v;
        }
    }
    const float* lrow = &xp[w][(lane & 15)*68];
    a_frag(lrow, 0, g4, ah0, al0);
    a_frag(lrow, 1, g4, ah1, al1);
    mm64(ah0, al0, ah1, al1, pWm, lane, acc);
#pragma unroll
    for (int nt = 0; nt < 4; ++nt) {
        int c = nt*16 + (lane & 15);
        float bc = bm[c];
        float w0t = Wmt[0*64+c], w1t = Wmt[1*64+c], w2t = Wmt[2*64+c];
#pragma unroll
        for (int reg = 0; reg < 4; ++reg) {
            int r = r0 + rloc + reg;
            float v = acc[nt][reg] + bc + rel[r*3+0]*w0t + rel[r*3+1]*w1t + rel[r*3+2]*w2t;
            h[(size_t)r*64 + c] = fmaxf(v, 0.f);
        }
    }
}

__global__ __launch_bounds__(256) void k_l2m_pre2_g(
    const float* __restrict__ c4, const int* __restrict__ lab,
    const unsigned short* __restrict__ pWl, const float* __restrict__ bl,
    const float* __restrict__ Wlt, const float* __restrict__ rel,
    const unsigned short* __restrict__ pWf2, const float* __restrict__ Wf2t,
    const float* __restrict__ pts,
    const float* __restrict__ Wh, const float* __restrict__ bh,
    const float* __restrict__ bf,
    float* __restrict__ x5, __half* __restrict__ p16, float* __restrict__ q, int ntiles)
{
    __shared__ float xp[4][16*68];
    __shared__ float dd[4][64];
    int lane = threadIdx.x & 63;
    int w = threadIdx.x >> 6;
    int tile = blockIdx.x*4 + w;
    if (tile >= ntiles) return;
    int r0 = tile*16;
    int g4 = (lane >> 4) * 4;
    int rloc = (lane >> 4) * 4;
    int rA = r0 + (lane & 15);
    const float* rowp = c4 + (size_t)lab[rA] * 64;
    bf16x8 ah0, al0, ah1, al1;
    a_frag(rowp, 0, g4, ah0, al0);
    a_frag(rowp, 1, g4, ah1, al1);
    f32x4 acc[4];
    mm64(ah0, al0, ah1, al1, pWl, lane, acc);
#pragma unroll
    for (int nt = 0; nt < 4; ++nt) {
        int c = nt*16 + (lane & 15);
        float bc = bl[c];
        float w0t = Wlt[0*64+c], w1t = Wlt[1*64+c], w2t = Wlt[2*64+c];
#pragma unroll
        for (int reg = 0; reg < 4; ++reg) {
            int r = r0 + rloc + reg;
            float v = acc[nt][reg] + bc + rel[r*3+0]*w0t + rel[r*3+1]*w1t + rel[r*3+2]*w2t;
            v = fmaxf(v, 0.f);
            x5[(size_t)r*64 + c] = v;
            xp[w][(rloc+reg)*68 + c] = v;
        }
    }
    {
        int rowl = lane & 15;
        int jj = lane >> 4;
        int j = jj < 3 ? jj : 2;
        float accd = 0.f;
#pragma unroll 16
        for (int k = 0; k < 64; ++k)
            accd = fmaf(xp[w][rowl*68 + k], Wh[k*3 + j], accd);
        dd[w][rowl*4 + jj] = tanhf(accd + bh[j]);
    }
    const float* lrow = &xp[w][(lane & 15)*68];
    a_frag(lrow, 0, g4, ah0, al0);
    a_frag(lrow, 1, g4, ah1, al1);
    mm64(ah0, al0, ah1, al1, pWf2, lane, acc);
#pragma unroll
    for (int nt = 0; nt < 4; ++nt) {
        int c = nt*16 + (lane & 15);
        float w0t = Wf2t[0*64+c], w1t = Wf2t[1*64+c], w2t = Wf2t[2*64+c];
        float bfc = bf[c];
#pragma unroll
        for (int reg = 0; reg < 4; ++reg) {
            int r = r0 + rloc + reg;
            int rl = rloc + reg;
            float p0 = pts[r*3+0], p1 = pts[r*3+1], p2 = pts[r*3+2];
            float v = acc[nt][reg] + p0*w0t + p1*w1t + p2*w2t;
            p16[(size_t)r*64 + c] = __float2half(v);
            float d0 = dd[w][rl*4+0], d1 = dd[w][rl*4+1], d2 = dd[w][rl*4+2];
            q[(size_t)r*64 + c] = (d0-p0)*w0t + (d1-p1)*w1t + (d2-p2)*w2t + bfc;
        }
    }
}

__global__ __launch_bounds__(256) void k_gemm_final(
    const float* __restrict__ agg, const unsigned short* __restrict__ pWg2,
    const float* __restrict__ bg2,
    const float* __restrict__ x5, const float* __restrict__ x2,
    const unsigned short* __restrict__ pW1, const float* __restrict__ b1,
    const float* __restrict__ W2, const float* __restrict__ b2,
    float* __restrict__ out, int ntiles)
{
    __shared__ float xp[4][16*68];
    int lane = threadIdx.x & 63;
    int w = threadIdx.x >> 6;
    int tile = blockIdx.x*4 + w;
    if (tile >= ntiles) return;
    int r0 = tile*16;
    int g4 = (lane >> 4) * 4;
    int rloc = (lane >> 4) * 4;
    const float* rowp = agg + (size_t)(r0 + (lane & 15)) * 64;
    bf16x8 ah0, al0, ah1, al1;
    a_frag(rowp, 0, g4, ah0, al0);
    a_frag(rowp, 1, g4, ah1, al1);
    f32x4 acc[4];
    mm64(ah0, al0, ah1, al1, pWg2, lane, acc);
#pragma unroll
    for (int nt = 0; nt < 4; ++nt) {
        int c = nt*16 + (lane & 15);
        float bc = bg2[c];
#pragma unroll
        for (int reg = 0; reg < 4; ++reg) {
            int r = r0 + rloc + reg;
            float v = fmaxf(acc[nt][reg] + bc, 0.f)
                    + x5[(size_t)r*64 + c] + x2[(size_t)r*64 + c];
            xp[w][(rloc+reg)*68 + c] = v;
        }
    }
    const float* lrow = &xp[w][(lane & 15)*68];
    a_frag(lrow, 0, g4, ah0, al0);
    a_frag(lrow, 1, g4, ah1, al1);
    mm64(ah0, al0, ah1, al1, pW1, lane, acc);
    float part0[4] = {0.f,0.f,0.f,0.f};
    float part1[4] = {0.f,0.f,0.f,0.f};
    float part2[4] = {0.f,0.f,0.f,0.f};
    float part3[4] = {0.f,0.f,0.f,0.f};
#pragma unroll
    for (int nt = 0; nt < 4; ++nt) {
        int c = nt*16 + (lane & 15);
        float bc = b1[c];
        float4 w2v = *(const float4*)(W2 + c*4);
#pragma unroll
        for (int reg = 0; reg < 4; ++reg) {
            float t = fmaxf(acc[nt][reg] + bc, 0.f);
            part0[reg] = fmaf(t, w2v.x, part0[reg]);
            part1[reg] = fmaf(t, w2v.y, part1[reg]);
            part2[reg] = fmaf(t, w2v.z, part2[reg]);
            part3[reg] = fmaf(t, w2v.w, part3[reg]);
        }
    }
#pragma unroll
    for (int m = 1; m < 16; m <<= 1) {
#pragma unroll
        for (int reg = 0; reg < 4; ++reg) {
            part0[reg] += __shfl_xor(part0[reg], m);
            part1[reg] += __shfl_xor(part1[reg], m);
            part2[reg] += __shfl_xor(part2[reg], m);
            part3[reg] += __shfl_xor(part3[reg], m);
        }
    }
    if ((lane & 15) == 0) {
        float b20 = b2[0], b21 = b2[1], b22 = b2[2], b23 = b2[3];
#pragma unroll
        for (int reg = 0; reg < 4; ++reg) {
            int r = r0 + rloc + reg;
            *(float4*)(out + (size_t)r*4) =
                make_float4(part0[reg]+b20, part1[reg]+b21, part2[reg]+b22, part3[reg]+b23);
        }
    }
}

// ================= segmax (fp16 p, half2-wide) + M-sized VALU kernels ==========
// Monotone RNE rounding => max of fp16(p) == fp16(max p): exact-max semantics.

__global__ __launch_bounds__(256) void k_seg_max_gnn(
    const int* __restrict__ rs, const int* __restrict__ srcs,
    const __half* __restrict__ p, float* __restrict__ q, int n)
{
    int lane = threadIdx.x & 63;
    int hf   = lane >> 5;
    int cl   = lane & 31;
    int wid  = blockIdx.x * (blockDim.x >> 6) + (threadIdx.x >> 6);
    int nw   = gridDim.x * (blockDim.x >> 6);
    const __half2* p2 = (const __half2*)p;     // 32 half2 per row (128 B)
    for (int d = wid; d < n; d += nw) {
        int du = __builtin_amdgcn_readfirstlane(d);
        int beg = rs[du], end = rs[du+1];
        float ax[8], ay[8];
#pragma unroll
        for (int u = 0; u < 8; ++u) { ax[u] = -1e30f; ay[u] = -1e30f; }
        int c = beg;
        while (c + 16 <= end) {
            int s[8];
#pragma unroll
            for (int u = 0; u < 8; ++u) s[u] = srcs[c + 2*u + hf];
#pragma unroll
            for (int u = 0; u < 8; ++u) {
                float2 v = __half22float2(p2[(size_t)s[u]*32 + cl]);
                ax[u] = fmaxf(ax[u], v.x);
                ay[u] = fmaxf(ay[u], v.y);
            }
            c += 16;
        }
        while (c + 8 <= end) {
            int s0 = srcs[c + hf],     s1 = srcs[c + 2 + hf];
            int s2 = srcs[c + 4 + hf], s3 = srcs[c + 6 + hf];
            float2 v0 = __half22float2(p2[(size_t)s0*32 + cl]);
            float2 v1 = __half22float2(p2[(size_t)s1*32 + cl]);
            float2 v2 = __half22float2(p2[(size_t)s2*32 + cl]);
            float2 v3 = __half22float2(p2[(size_t)s3*32 + cl]);
            ax[0] = fmaxf(ax[0], v0.x); ay[0] = fmaxf(ay[0], v0.y);
            ax[1] = fmaxf(ax[1], v1.x); ay[1] = fmaxf(ay[1], v1.y);
            ax[2] = fmaxf(ax[2], v2.x); ay[2] = fmaxf(ay[2], v2.y);
            ax[3] = fmaxf(ax[3], v3.x); ay[3] = fmaxf(ay[3], v3.y);
            c += 8;
        }
        while (c + 2 <= end) {
            int s0 = srcs[c + hf];
            float2 v = __half22float2(p2[(size_t)s0*32 + cl]);
            ax[0] = fmaxf(ax[0], v.x);
            ay[0] = fmaxf(ay[0], v.y);
            c += 2;
        }
        if (c < end) {
            int s0 = srcs[c];
            float2 v = __half22float2(p2[(size_t)s0*32 + cl]);
            ax[0] = fmaxf(ax[0], v.x);
            ay[0] = fmaxf(ay[0], v.y);
        }
        float mx = fmaxf(fmaxf(fmaxf(ax[0],ax[1]), fmaxf(ax[2],ax[3])),
                         fmaxf(fmaxf(ax[4],ax[5]), fmaxf(ax[6],ax[7])));
        float my = fmaxf(fmaxf(fmaxf(ay[0],ay[1]), fmaxf(ay[2],ay[3])),
                         fmaxf(fmaxf(ay[4],ay[5]), fmaxf(ay[6],ay[7])));
        mx = fmaxf(mx, __shfl_xor(mx, 32));
        my = fmaxf(my, __shfl_xor(my, 32));
        if (hf == 0) {
            float2* q2 = (float2*)q;
            size_t o = (size_t)du*32 + cl;
            float2 qv = q2[o];
            q2[o] = make_float2(fmaxf(mx + qv.x, 0.f), fmaxf(my + qv.y, 0.f));
        }
    }
}

__global__ __launch_bounds__(256, 2) void k_seglab_pre1(
    const int* __restrict__ rsL, const int* __restrict__ srcsL,
    const float* __restrict__ h, const float* __restrict__ pos,
    const float* __restrict__ Wh, const float* __restrict__ bh,
    const float* __restrict__ Wf, const float* __restrict__ bf,
    float* __restrict__ c, __half* __restrict__ pa, float* __restrict__ qa, int m)
{
    int lane = threadIdx.x & 63;
    int wid  = blockIdx.x * (blockDim.x >> 6) + (threadIdx.x >> 6);
    int nw   = gridDim.x * (blockDim.x >> 6);
    REPD(WLOAD, wc, Wf + 3*64)
    float w0 = Wf[0*64+lane], w1 = Wf[1*64+lane], w2 = Wf[2*64+lane];
    float bfl = bf[lane];
    float wh0 = Wh[lane*3+0], wh1 = Wh[lane*3+1], wh2 = Wh[lane*3+2];
    float bh0 = bh[0], bh1 = bh[1], bh2 = bh[2];
    for (int d0 = wid*2; d0 < m; d0 += nw*2) {
        int dA = __builtin_amdgcn_readfirstlane(d0);
        int dB = dA + 1;
        int begA = rsL[dA], endA = rsL[dA+1], endB = rsL[dA+2];
        int ca = begA, cb = endA;
        float aA0=-1e30f, aA1=-1e30f, aB0=-1e30f, aB1=-1e30f;
        while (ca+2 <= endA && cb+2 <= endB) {
            int s0=srcsL[ca], s1=srcsL[ca+1], s2=srcsL[cb], s3=srcsL[cb+1];
            aA0 = fmaxf(aA0, h[(size_t)s0*64+lane]);
            aA1 = fmaxf(aA1, h[(size_t)s1*64+lane]);
            aB0 = fmaxf(aB0, h[(size_t)s2*64+lane]);
            aB1 = fmaxf(aB1, h[(size_t)s3*64+lane]);
            ca += 2; cb += 2;
        }
        while (ca+2 <= endA) {
            int s0=srcsL[ca], s1=srcsL[ca+1];
            aA0 = fmaxf(aA0, h[(size_t)s0*64+lane]);
            aA1 = fmaxf(aA1, h[(size_t)s1*64+lane]);
            ca += 2;
        }
        while (cb+2 <= endB) {
            int s2=srcsL[cb], s3=srcsL[cb+1];
            aB0 = fmaxf(aB0, h[(size_t)s2*64+lane]);
            aB1 = fmaxf(aB1, h[(size_t)s3*64+lane]);
            cb += 2;
        }
        if (ca < endA) aA0 = fmaxf(aA0, h[(size_t)srcsL[ca]*64+lane]);
        if (cb < endB) aB0 = fmaxf(aB0, h[(size_t)srcsL[cb]*64+lane]);
        float cvA = fmaxf(fmaxf(aA0,aA1), 0.f);
        float cvB = fmaxf(fmaxf(aB0,aB1), 0.f);
        c[(size_t)dA*64+lane] = cvA;
        c[(size_t)dB*64+lane] = cvB;
        float d0A = cvA*wh0, d1A = cvA*wh1, d2A = cvA*wh2;
        float d0B = cvB*wh0, d1B = cvB*wh1, d2B = cvB*wh2;
#pragma unroll
        for (int o = 32; o; o >>= 1) {
            d0A += __shfl_xor(d0A,o); d1A += __shfl_xor(d1A,o); d2A += __shfl_xor(d2A,o);
            d0B += __shfl_xor(d0B,o); d1B += __shfl_xor(d1B,o); d2B += __shfl_xor(d2B,o);
        }
        d0A = tanhf(d0A+bh0); d1A = tanhf(d1A+bh1); d2A = tanhf(d2A+bh2);
        d0B = tanhf(d0B+bh0); d1B = tanhf(d1B+bh1); d2B = tanhf(d2B+bh2);
        float pA0 = pos[dA*3+0], pA1 = pos[dA*3+1], pA2 = pos[dA*3+2];
        float pB0 = pos[dB*3+0], pB1 = pos[dB*3+1], pB2 = pos[dB*3+2];
        float s0A=0.f, s1A=0.f, s0B=0.f, s1B=0.f;
        REPP(WFMA, wc, cvA, s0A, s1A)
        REPP(WFMA, wc, cvB, s0B, s1B)
        pa[(size_t)dA*64+lane] = __float2half(s0A+s1A + pA0*w0 + pA1*w1 + pA2*w2);
        pa[(size_t)dB*64+lane] = __float2half(s0B+s1B + pB0*w0 + pB1*w1 + pB2*w2);
        qa[(size_t)dA*64+lane] = (d0A-pA0)*w0 + (d1A-pA1)*w1 + (d2A-pA2)*w2 + bfl;
        qa[(size_t)dB*64+lane] = (d0B-pB0)*w0 + (d1B-pB1)*w1 + (d2B-pB2)*w2 + bfl;
    }
}

__global__ __launch_bounds__(256, 2) void k_gnn_post(
    const float* __restrict__ agg, const float* __restrict__ Wg,
    const float* __restrict__ bg, const float* __restrict__ xres,
    float* __restrict__ out, int n)
{
    int lane = threadIdx.x & 63;
    int wid  = blockIdx.x * (blockDim.x >> 6) + (threadIdx.x >> 6);
    int nw   = gridDim.x * (blockDim.x >> 6);
    REPD(WLOAD, wg, Wg)
    float bgl = bg[lane];
    for (int i0 = wid*2; i0 < n; i0 += nw*2) {
        int iA = __builtin_amdgcn_readfirstlane(i0);
        size_t oA = (size_t)iA*64 + lane, oB = oA + 64;
        float avA = agg[oA], avB = agg[oB];
        float s0A=0.f, s1A=0.f, s0B=0.f, s1B=0.f;
        REPP(WFMA, wg, avA, s0A, s1A)
        REPP(WFMA, wg, avB, s0B, s1B)
        out[oA] = fmaxf(s0A+s1A + bgl, 0.f) + xres[oA];
        out[oB] = fmaxf(s0B+s1B + bgl, 0.f) + xres[oB];
    }
}

// ---------------- launch ----------------

extern "C" void kernel_launch(void* const* d_in, const int* in_sizes, int n_in,
                              void* d_out, int out_size, void* d_ws, size_t ws_size,
                              hipStream_t stream)
{
    const int N = 100000, M = 10000, E0 = 1600000, E1 = 320000;
    const int NB0 = (N + 255) / 256;
    const int NB1 = (M + 255) / 256;
    const int NBL = (M + 255) / 256;
    const int GB0 = (E0 + EPB - 1) / EPB;
    const int GB1 = (E1 + EPB - 1) / EPB;
    const int GBL = (N + EPB - 1) / EPB;

    const float* feat = (const float*)d_in[0];
    const float* pts  = (const float*)d_in[1];
    const float* ctr  = (const float*)d_in[2];
    const int*   lab  = (const int*)d_in[3];
    const int2*  e0   = (const int2*)d_in[4];
    const int2*  e1   = (const int2*)d_in[5];
    const float* feW  = (const float*)d_in[6];
    const float* feb  = (const float*)d_in[7];
    const float* Wh   = (const float*)d_in[8];
    const float* bh   = (const float*)d_in[9];
    const float* Wf   = (const float*)d_in[10];
    const float* bf   = (const float*)d_in[11];
    const float* Wg   = (const float*)d_in[12];
    const float* bg   = (const float*)d_in[13];
    const float* m2lW = (const float*)d_in[14];
    const float* m2lb = (const float*)d_in[15];
    const float* l2mW = (const float*)d_in[16];
    const float* l2mb = (const float*)d_in[17];
    const float* cW1  = (const float*)d_in[18];
    const float* cb1  = (const float*)d_in[19];
    const float* cW2  = (const float*)d_in[20];
    const float* cb2  = (const float*)d_in[21];
    float* out = (float*)d_out;

    char* ws = (char*)d_ws;
    size_t off = 0;
    auto alloc = [&](size_t bytes) -> char* {
        char* r = ws + off; off += (bytes + 255) & ~(size_t)255; return r;
    };
    float*  rel  = (float*)alloc((size_t)N*3*4);
    float*  x1   = (float*)alloc((size_t)N*64*4);
    float*  x2   = (float*)alloc((size_t)N*64*4);   // hosts ebufs pre-compute
    float*  p    = (float*)alloc((size_t)N*64*4);   // h (fp32 label-segmax input)
    float*  q    = (float*)alloc((size_t)N*64*4);
    __half* p16  = (__half*)alloc((size_t)N*64*2);  // fp16 gather buffer (p0/p1/p2)
    float*  c    = (float*)alloc((size_t)M*64*4);
    float*  c4   = (float*)alloc((size_t)M*64*4);
    int* rs0     = (int*)alloc((size_t)(N+2)*4);
    int* srcs0   = (int*)alloc((size_t)E0*4);
    int* rs1     = (int*)alloc((size_t)(M+2)*4);
    int* srcs1   = (int*)alloc((size_t)E1*4);
    int* rsL     = (int*)alloc((size_t)(M+2)*4);
    int* srcsL   = (int*)alloc((size_t)N*4);
    int* cnt0    = (int*)alloc((size_t)NB0*4);
    int* cnt1    = (int*)alloc((size_t)NB1*4);
    int* cntL    = (int*)alloc((size_t)NBL*4);
    int* base0   = (int*)alloc((size_t)(NB0+1)*4);
    int* base1   = (int*)alloc((size_t)(NB1+1)*4);
    int* baseL   = (int*)alloc((size_t)(NBL+1)*4);
    int* cur0    = (int*)alloc((size_t)NB0*4);
    int* cur1    = (int*)alloc((size_t)NB1*4);
    int* curL    = (int*)alloc((size_t)NBL*4);
    unsigned short* pWf0  = (unsigned short*)alloc(8192*2);
    unsigned short* pWg0  = (unsigned short*)alloc(8192*2);
    unsigned short* pWm   = (unsigned short*)alloc(8192*2);
    unsigned short* pWl2m = (unsigned short*)alloc(8192*2);
    unsigned short* pWf2  = (unsigned short*)alloc(8192*2);
    unsigned short* pWg2  = (unsigned short*)alloc(8192*2);
    unsigned short* pW1   = (unsigned short*)alloc(8192*2);
    (void)ws_size; (void)in_sizes; (void)n_in; (void)out_size;

    int2* ebuf0 = (int2*)x2;
    int2* ebuf1 = ebuf0 + E0;
    int2* ebufL = ebuf1 + E1;

    dim3 blk(256);
    const int gridM = 640, gSeg = 2048;
    const int NT = N / 16;
    const int gG = (NT + 3) / 4;

    // ---- zero (separate launch: MUST complete before k_prep's hist atomics) ----
    k_zero3<<<1, blk, 0, stream>>>(cnt0, NB0, cnt1, NB1, cntL, NBL);
    // ---- merged pack (7 blocks) + hist (1536 blocks) ----
    k_prep<<<7 + 1536, blk, 0, stream>>>(
        Wf + 0*67*64 + 3*64, pWf0,
        Wg + 0*64*64,        pWg0,
        m2lW,                pWm,
        l2mW,                pWl2m,
        Wf + 2*67*64 + 3*64, pWf2,
        Wg + 2*64*64,        pWg2,
        cW1,                 pW1,
        cnt0, NB0, cnt1, NB1, cntL, NBL,
        e0, E0, e1, E1, lab, N);
    k_bscan3<<<3, 512, 0, stream>>>(cnt0, base0, cur0, NB0, E0,
                                    cnt1, base1, cur1, NB1, E1,
                                    cntL, baseL, curL, NBL, N);
    k_bucket3<<<GB0 + GB1 + GBL, BKT, 0, stream>>>(
        e0, cur0, ebuf0, E0, NB0, GB0,
        e1, cur1, ebuf1, E1, NB1, GB1,
        lab, curL, ebufL, N, NBL);
    k_final3<<<NB0 + NB1 + NBL, 512, 0, stream>>>(
        ebuf0, base0, rs0, srcs0, N, E0, NB0,
        ebuf1, base1, rs1, srcs1, M, E1, NB1,
        ebufL, baseL, rsL, srcsL, M, N, NBL);

    // ---- layer 0 ----
    k_feat_pre0_g<<<gG, blk, 0, stream>>>(feat, pts, ctr, lab, feW, feb,
                                          Wh+0*64*3, bh+0*3,
                                          pWf0, Wf+0*67*64, bf+0*64,
                                          rel, x1, p16, q, NT);
    k_seg_max_gnn<<<gSeg, blk, 0, stream>>>(rs0, srcs0, p16, q, N);
    k_post_m2l_g<<<gG, blk, 0, stream>>>(q, pWg0, bg+0*64, x1,
                                         pWm, m2lb, m2lW+64*64, rel,
                                         x2, p, NT);                        // h -> p (fp32)

    // ---- layer 1 (clusters, VALU) ----
    float* q1 = q + (size_t)M*64;
    k_seglab_pre1<<<gridM, blk, 0, stream>>>(rsL, srcsL, p, ctr,
                                             Wh+1*64*3, bh+1*3, Wf+1*67*64, bf+1*64,
                                             c, p16, q1, M);               // pa -> p16
    k_seg_max_gnn<<<640, blk, 0, stream>>>(rs1, srcs1, p16, q1, M);
    k_gnn_post<<<gridM, blk, 0, stream>>>(q1, Wg+1*64*64, bg+1*64, c, c4, M);

    // ---- l2m (+q fold) + layer 2 + classifier ----
    k_l2m_pre2_g<<<gG, blk, 0, stream>>>(c4, lab, pWl2m, l2mb, l2mW+64*64, rel,
                                         pWf2, Wf+2*67*64, pts,
                                         Wh+2*64*3, bh+2*3, bf+2*64,
                                         x1, p16, q, NT);                   // x5 -> x1
    k_seg_max_gnn<<<gSeg, blk, 0, stream>>>(rs0, srcs0, p16, q, N);
    k_gemm_final<<<gG, blk, 0, stream>>>(q, pWg2, bg+2*64, x1, x2,
                                         pW1, cb1, cW2, cb2, out, NT);
}

// Round 17
// 293.123 us; speedup vs baseline: 1.1485x; 1.0065x over previous
//
#include <hip/hip_runtime.h>
#include <hip/hip_fp16.h>

// ---------------- helpers ----------------

__device__ __forceinline__ float bcast(float v, int l) {
    return __int_as_float(__builtin_amdgcn_readlane(__float_as_int(v), l));
}

#define REPD(M,P,B) \
 M(0,P,B)  M(1,P,B)  M(2,P,B)  M(3,P,B)  M(4,P,B)  M(5,P,B)  M(6,P,B)  M(7,P,B) \
 M(8,P,B)  M(9,P,B)  M(10,P,B) M(11,P,B) M(12,P,B) M(13,P,B) M(14,P,B) M(15,P,B) \
 M(16,P,B) M(17,P,B) M(18,P,B) M(19,P,B) M(20,P,B) M(21,P,B) M(22,P,B) M(23,P,B) \
 M(24,P,B) M(25,P,B) M(26,P,B) M(27,P,B) M(28,P,B) M(29,P,B) M(30,P,B) M(31,P,B) \
 M(32,P,B) M(33,P,B) M(34,P,B) M(35,P,B) M(36,P,B) M(37,P,B) M(38,P,B) M(39,P,B) \
 M(40,P,B) M(41,P,B) M(42,P,B) M(43,P,B) M(44,P,B) M(45,P,B) M(46,P,B) M(47,P,B) \
 M(48,P,B) M(49,P,B) M(50,P,B) M(51,P,B) M(52,P,B) M(53,P,B) M(54,P,B) M(55,P,B) \
 M(56,P,B) M(57,P,B) M(58,P,B) M(59,P,B) M(60,P,B) M(61,P,B) M(62,P,B) M(63,P,B)

#define WLOAD(J,P,B) float P##J = (B)[(J)*64+lane];

#define REPP(M,P,X,S0,S1) \
 M(0,1,P,X,S0,S1)  M(2,3,P,X,S0,S1)  M(4,5,P,X,S0,S1)  M(6,7,P,X,S0,S1) \
 M(8,9,P,X,S0,S1)  M(10,11,P,X,S0,S1) M(12,13,P,X,S0,S1) M(14,15,P,X,S0,S1) \
 M(16,17,P,X,S0,S1) M(18,19,P,X,S0,S1) M(20,21,P,X,S0,S1) M(22,23,P,X,S0,S1) \
 M(24,25,P,X,S0,S1) M(26,27,P,X,S0,S1) M(28,29,P,X,S0,S1) M(30,31,P,X,S0,S1) \
 M(32,33,P,X,S0,S1) M(34,35,P,X,S0,S1) M(36,37,P,X,S0,S1) M(38,39,P,X,S0,S1) \
 M(40,41,P,X,S0,S1) M(42,43,P,X,S0,S1) M(44,45,P,X,S0,S1) M(46,47,P,X,S0,S1) \
 M(48,49,P,X,S0,S1) M(50,51,P,X,S0,S1) M(52,53,P,X,S0,S1) M(54,55,P,X,S0,S1) \
 M(56,57,P,X,S0,S1) M(58,59,P,X,S0,S1) M(60,61,P,X,S0,S1) M(62,63,P,X,S0,S1)

#define WFMA(J,K,P,X,S0,S1) \
 S0 = fmaf(bcast(X,J), P##J, S0); \
 S1 = fmaf(bcast(X,K), P##K, S1);

// ---------------- MFMA split-bf16 machinery ----------------

typedef short bf16x8 __attribute__((ext_vector_type(8)));
typedef float f32x4  __attribute__((ext_vector_type(4)));

__device__ __forceinline__ unsigned short f2bf_rne(float x) {
    unsigned u = __float_as_uint(x);
    unsigned r = u + 0x7FFFu + ((u >> 16) & 1u);
    return (unsigned short)(r >> 16);
}

__device__ __forceinline__ void a_frag(const float* __restrict__ row, int kt, int g4,
                                       bf16x8& ah, bf16x8& al)
{
    const float4 a0 = *(const float4*)(row + kt*32 + g4);
    const float4 a1 = *(const float4*)(row + kt*32 + 16 + g4);
    float v0 = a0.x, v1 = a0.y, v2 = a0.z, v3 = a0.w;
    float v4 = a1.x, v5 = a1.y, v6 = a1.z, v7 = a1.w;
#define CVT1(idx, val) { \
    unsigned short hh = f2bf_rne(val); \
    float lf = (val) - __uint_as_float((unsigned)hh << 16); \
    ah[idx] = (short)hh; al[idx] = (short)f2bf_rne(lf); }
    CVT1(0,v0) CVT1(1,v1) CVT1(2,v2) CVT1(3,v3)
    CVT1(4,v4) CVT1(5,v5) CVT1(6,v6) CVT1(7,v7)
#undef CVT1
}

__device__ __forceinline__ void mm64(const bf16x8& ah0, const bf16x8& al0,
                                     const bf16x8& ah1, const bf16x8& al1,
                                     const unsigned short* __restrict__ pW,
                                     int lane, f32x4 acc[4])
{
#pragma unroll
    for (int nt = 0; nt < 4; ++nt) {
        f32x4 a = {0.f, 0.f, 0.f, 0.f};
#pragma unroll
        for (int kt = 0; kt < 2; ++kt) {
            bf16x8 bh = *(const bf16x8*)(pW + (kt*4+nt)*1024 + lane*8);
            bf16x8 bl = *(const bf16x8*)(pW + (kt*4+nt)*1024 + 512 + lane*8);
            bf16x8 aH = kt ? ah1 : ah0;
            bf16x8 aL = kt ? al1 : al0;
            a = __builtin_amdgcn_mfma_f32_16x16x32_bf16(aH, bh, a, 0, 0, 0);
            a = __builtin_amdgcn_mfma_f32_16x16x32_bf16(aL, bh, a, 0, 0, 0);
            a = __builtin_amdgcn_mfma_f32_16x16x32_bf16(aH, bl, a, 0, 0, 0);
        }
        acc[nt] = a;
    }
}

// ================= prep: packB (blocks 0..6) + bhist (blocks 7..1542) ============
// cnt* MUST be zeroed by the preceding k_zero3 launch (r14 lesson).

#define BKT 512
#define EPT 8
#define EPB (BKT*EPT)

__global__ __launch_bounds__(256) void k_prep(
    const float* W0, unsigned short* d0, const float* W1, unsigned short* d1,
    const float* W2, unsigned short* d2, const float* W3, unsigned short* d3,
    const float* W4, unsigned short* d4, const float* W5, unsigned short* d5,
    const float* W6, unsigned short* d6,
    int* cnt0, int nb0, int* cnt1, int nb1, int* cntL, int nbL,
    const int2* __restrict__ e0, int E0,
    const int2* __restrict__ e1, int E1,
    const int* __restrict__ lab, int NN)
{
    int b = blockIdx.x;
    if (b < 7) {
        const float* W; unsigned short* dst;
        switch (b) {
            case 0: W=W0; dst=d0; break;
            case 1: W=W1; dst=d1; break;
            case 2: W=W2; dst=d2; break;
            case 3: W=W3; dst=d3; break;
            case 4: W=W4; dst=d4; break;
            case 5: W=W5; dst=d5; break;
            default: W=W6; dst=d6; break;
        }
        int t = threadIdx.x;
        for (int slot = t; slot < 512; slot += 256) {
            int frag = slot >> 6;
            int lane = slot & 63;
            int kt = frag >> 2, nt = frag & 3;
            int g4 = (lane >> 4) * 4, n = nt*16 + (lane & 15);
            for (int j = 0; j < 8; ++j) {
                int k = kt*32 + (j>>2)*16 + g4 + (j&3);
                float x = W[k*64 + n];
                unsigned short hh = f2bf_rne(x);
                float lf = x - __uint_as_float((unsigned)hh << 16);
                dst[frag*1024 + 0*512 + lane*8 + j] = hh;
                dst[frag*1024 + 1*512 + lane*8 + j] = f2bf_rne(lf);
            }
        }
        return;
    }
    {
        const int2* e = nullptr; const int* lv = nullptr; int* gcnt; int total; int nb;
        int bloc, nblocks;
        int bb = b - 7;
        if (bb < 1024)      { e = e0; gcnt = cnt0; total = E0; nb = nb0; bloc = bb;        nblocks = 1024; }
        else if (bb < 1280) { e = e1; gcnt = cnt1; total = E1; nb = nb1; bloc = bb - 1024; nblocks = 256; }
        else                { lv = lab; gcnt = cntL; total = NN; nb = nbL; bloc = bb - 1280; nblocks = 256; }
        __shared__ int c[400];
        for (int i = threadIdx.x; i < nb; i += 256) c[i] = 0;
        __syncthreads();
        for (int idx = bloc*256 + threadIdx.x; idx < total; idx += nblocks*256)
            atomicAdd(&c[(lv ? lv[idx] : e[idx].y) >> 8], 1);
        __syncthreads();
        for (int i = threadIdx.x; i < nb; i += 256) if (c[i]) atomicAdd(&gcnt[i], c[i]);
    }
}

__global__ __launch_bounds__(256) void k_zero3(
    int* c0, int n0, int* c1, int n1, int* c2, int n2)
{
    int t = threadIdx.x;
    for (int i = t; i < n0; i += 256) c0[i] = 0;
    for (int i = t; i < n1; i += 256) c1[i] = 0;
    for (int i = t; i < n2; i += 256) c2[i] = 0;
}

__global__ __launch_bounds__(512) void k_bscan3(
    const int* c0, int* b0, int* u0, int nb0, int t0,
    const int* c1, int* b1, int* u1, int nb1, int t1,
    const int* c2, int* b2, int* u2, int nb2, int t2)
{
    const int* cnt; int* base; int* cur; int nb; int tot;
    if (blockIdx.x == 0) { cnt=c0; base=b0; cur=u0; nb=nb0; tot=t0; }
    else if (blockIdx.x == 1) { cnt=c1; base=b1; cur=u1; nb=nb1; tot=t1; }
    else { cnt=c2; base=b2; cur=u2; nb=nb2; tot=t2; }
    __shared__ int sc[512];
    int t = threadIdx.x;
    int v = (t < nb) ? cnt[t] : 0;
    sc[t] = v; __syncthreads();
    for (int o = 1; o < 512; o <<= 1) {
        int a = (t >= o) ? sc[t-o] : 0;
        __syncthreads();
        sc[t] += a;
        __syncthreads();
    }
    if (t < nb) { int ex = sc[t] - v; base[t] = ex; cur[t] = ex; }
    if (t == nb) base[nb] = tot;
}

__global__ __launch_bounds__(BKT) void k_bucket3(
    const int2* __restrict__ e0, int* cur0, int2* eb0, int E0, int nb0, int GB0,
    const int2* __restrict__ e1, int* cur1, int2* eb1, int E1, int nb1, int GB1,
    const int* __restrict__ lab, int* curL, int2* ebL, int NN, int nbL)
{
    const int2* e = nullptr; const int* lv = nullptr; int* cur; int2* ebuf;
    int total; int nb; int bloc;
    int b = blockIdx.x;
    if (b < GB0)            { e = e0; cur = cur0; ebuf = eb0; total = E0; nb = nb0; bloc = b; }
    else if (b < GB0 + GB1) { e = e1; cur = cur1; ebuf = eb1; total = E1; nb = nb1; bloc = b - GB0; }
    else                    { lv = lab; cur = curL; ebuf = ebL; total = NN; nb = nbL; bloc = b - GB0 - GB1; }
    __shared__ int cnt[400];
    __shared__ int chunk[400];
    int t = threadIdx.x;
    int base = bloc * EPB;
    for (int i = t; i < nb; i += BKT) cnt[i] = 0;
    __syncthreads();
    int2 ed[EPT]; int rk[EPT];
#pragma unroll
    for (int k = 0; k < EPT; ++k) {
        int idx = base + k*BKT + t;
        if (idx < total) {
            ed[k] = lv ? make_int2(idx, lv[idx]) : e[idx];
            rk[k] = atomicAdd(&cnt[ed[k].y >> 8], 1);
        } else rk[k] = -1;
    }
    __syncthreads();
    for (int i = t; i < nb; i += BKT) { int c = cnt[i]; if (c) chunk[i] = atomicAdd(&cur[i], c); }
    __syncthreads();
#pragma unroll
    for (int k = 0; k < EPT; ++k)
        if (rk[k] >= 0) ebuf[chunk[ed[k].y >> 8] + rk[k]] = ed[k];
}

__global__ __launch_bounds__(512) void k_final3(
    const int2* eb0, const int* base0, int* rs0, int* srcs0, int nd0, int et0, int NB0_,
    const int2* eb1, const int* base1, int* rs1, int* srcs1, int nd1, int et1, int NB1_,
    const int2* ebL, const int* baseL, int* rsL, int* srcsL, int ndL, int etL, int NBL_)
{
    const int2* ebuf; const int* base_; int* rs; int* srcs; int ndst; int etot; int nb; int bloc;
    int b = blockIdx.x;
    if (b < NB0_)              { ebuf=eb0; base_=base0; rs=rs0; srcs=srcs0; ndst=nd0; etot=et0; nb=NB0_; bloc=b; }
    else if (b < NB0_ + NB1_)  { ebuf=eb1; base_=base1; rs=rs1; srcs=srcs1; ndst=nd1; etot=et1; nb=NB1_; bloc=b-NB0_; }
    else                       { ebuf=ebL; base_=baseL; rs=rsL; srcs=srcsL; ndst=ndL; etot=etL; nb=NBL_; bloc=b-NB0_-NB1_; }
    __shared__ int h[256];
    __shared__ int sc[256];
    int t = threadIdx.x;
    int base = base_[bloc];
    int cnt  = base_[bloc+1] - base;
    int d0 = bloc << 8;
    if (t < 256) h[t] = 0;
    __syncthreads();
    for (int i = t; i < cnt; i += 512) atomicAdd(&h[ebuf[base+i].y - d0], 1);
    __syncthreads();
    int v = (t < 256) ? h[t] : 0;
    if (t < 256) sc[t] = v;
    __syncthreads();
    for (int o = 1; o < 256; o <<= 1) {
        int a = (t < 256 && t >= o) ? sc[t-o] : 0;
        __syncthreads();
        if (t < 256) sc[t] += a;
        __syncthreads();
    }
    if (t < 256) {
        int gpos = base + sc[t] - v;
        if (d0 + t < ndst) rs[d0+t] = gpos;
        h[t] = gpos;
    }
    if (bloc == nb-1 && t == 0) rs[ndst] = etot;
    __syncthreads();
    for (int i = t; i < cnt; i += 512) {
        int2 ed = ebuf[base+i];
        int pos = atomicAdd(&h[ed.y - d0], 1);
        srcs[pos] = ed.x;
    }
}

// ================= fused MFMA compute kernels =================

__global__ __launch_bounds__(256) void k_feat_pre0_g(
    const float* __restrict__ feat, const float* __restrict__ pts,
    const float* __restrict__ ctr, const int* __restrict__ lab,
    const float* __restrict__ Wfe, const float* __restrict__ bfe,
    const float* __restrict__ Wh, const float* __restrict__ bh,
    const unsigned short* __restrict__ pWf0, const float* __restrict__ Wf0h,
    const float* __restrict__ bf0,
    float* __restrict__ rel, float* __restrict__ x1,
    __half* __restrict__ p16, float* __restrict__ q, int ntiles)
{
    __shared__ float xp[4][16*68];
    __shared__ float dd[4][64];
    int lane = threadIdx.x & 63;
    int w = threadIdx.x >> 6;
    int tile = blockIdx.x*4 + w;
    if (tile >= ntiles) return;
    int r0 = tile*16;
    int row = lane & 15;
    int cg  = lane >> 4;
    int r = r0 + row;
    int l = lab[r];
    float pr0 = pts[r*3+0], pr1 = pts[r*3+1], pr2 = pts[r*3+2];
    float rv0 = pr0 - ctr[l*3+0], rv1 = pr1 - ctr[l*3+1], rv2 = pr2 - ctr[l*3+2];
    if (cg == 0) { rel[r*3+0]=rv0; rel[r*3+1]=rv1; rel[r*3+2]=rv2; }
    float f0 = feat[r*4+0], f1 = feat[r*4+1], f2 = feat[r*4+2], f3 = feat[r*4+3];
#pragma unroll
    for (int k = 0; k < 16; ++k) {
        int c = cg*16 + k;
        float v = bfe[c];
        v = fmaf(f0, Wfe[0*64+c], v);
        v = fmaf(f1, Wfe[1*64+c], v);
        v = fmaf(f2, Wfe[2*64+c], v);
        v = fmaf(f3, Wfe[3*64+c], v);
        v = fmaf(rv0, Wfe[4*64+c], v);
        v = fmaf(rv1, Wfe[5*64+c], v);
        v = fmaf(rv2, Wfe[6*64+c], v);
        xp[w][row*68 + c] = fmaxf(v, 0.f);
    }
    {
        int j = cg < 3 ? cg : 2;
        float accd = 0.f;
#pragma unroll 16
        for (int k2 = 0; k2 < 64; ++k2)
            accd = fmaf(xp[w][row*68 + k2], Wh[k2*3 + j], accd);
        dd[w][row*4 + cg] = tanhf(accd + bh[j]);
    }
    int g4 = cg * 4;
    const float* lrow = &xp[w][row*68];
    bf16x8 ah0, al0, ah1, al1;
    a_frag(lrow, 0, g4, ah0, al0);
    a_frag(lrow, 1, g4, ah1, al1);
    f32x4 acc[4];
    mm64(ah0, al0, ah1, al1, pWf0, lane, acc);
    int rloc = cg*4;
#pragma unroll
    for (int nt = 0; nt < 4; ++nt) {
        int c = nt*16 + row;
        float w0t = Wf0h[0*64+c], w1t = Wf0h[1*64+c], w2t = Wf0h[2*64+c];
        float bfc = bf0[c];
#pragma unroll
        for (int reg = 0; reg < 4; ++reg) {
            int rr = r0 + rloc + reg;
            int rl = rloc + reg;
            float pp0 = pts[rr*3+0], pp1 = pts[rr*3+1], pp2 = pts[rr*3+2];
            float v = acc[nt][reg] + pp0*w0t + pp1*w1t + pp2*w2t;
            p16[(size_t)rr*64 + c] = __float2half(v);
            x1[(size_t)rr*64 + c] = xp[w][rl*68 + c];
            float d0 = dd[w][rl*4+0], d1 = dd[w][rl*4+1], d2 = dd[w][rl*4+2];
            q[(size_t)rr*64 + c] = (d0-pp0)*w0t + (d1-pp1)*w1t + (d2-pp2)*w2t + bfc;
        }
    }
}

__global__ __launch_bounds__(256) void k_post_m2l_g(
    const float* __restrict__ agg, const unsigned short* __restrict__ pWg,
    const float* __restrict__ bg, const float* __restrict__ x1,
    const unsigned short* __restrict__ pWm, const float* __restrict__ bm,
    const float* __restrict__ Wmt, const float* __restrict__ rel,
    float* __restrict__ x2, float* __restrict__ h, int ntiles)
{
    __shared__ float xp[4][16*68];
    int lane = threadIdx.x & 63;
    int w = threadIdx.x >> 6;
    int tile = blockIdx.x*4 + w;
    if (tile >= ntiles) return;
    int r0 = tile*16;
    int g4 = (lane >> 4) * 4;
    int rloc = (lane >> 4) * 4;
    const float* rowp = agg + (size_t)(r0 + (lane & 15)) * 64;
    bf16x8 ah0, al0, ah1, al1;
    a_frag(rowp, 0, g4, ah0, al0);
    a_frag(rowp, 1, g4, ah1, al1);
    f32x4 acc[4];
    mm64(ah0, al0, ah1, al1, pWg, lane, acc);
#pragma unroll
    for (int nt = 0; nt < 4; ++nt) {
        int c = nt*16 + (lane & 15);
        float bc = bg[c];
#pragma unroll
        for (int reg = 0; reg < 4; ++reg) {
            int r = r0 + rloc + reg;
            float v = fmaxf(acc[nt][reg] + bc, 0.f) + x1[(size_t)r*64 + c];
            x2[(size_t)r*64 + c] = v;
            xp[w][(rloc+reg)*68 + c] = v;
        }
    }
    const float* lrow = &xp[w][(lane & 15)*68];
    a_frag(lrow, 0, g4, ah0, al0);
    a_frag(lrow, 1, g4, ah1, al1);
    mm64(ah0, al0, ah1, al1, pWm, lane, acc);
#pragma unroll
    for (int nt = 0; nt < 4; ++nt) {
        int c = nt*16 + (lane & 15);
        float bc = bm[c];
        float w0t = Wmt[0*64+c], w1t = Wmt[1*64+c], w2t = Wmt[2*64+c];
#pragma unroll
        for (int reg = 0; reg < 4; ++reg) {
            int r = r0 + rloc + reg;
            float v = acc[nt][reg] + bc + rel[r*3+0]*w0t + rel[r*3+1]*w1t + rel[r*3+2]*w2t;
            h[(size_t)r*64 + c] = fmaxf(v, 0.f);
        }
    }
}

__global__ __launch_bounds__(256) void k_l2m_pre2_g(
    const float* __restrict__ c4, const int* __restrict__ lab,
    const unsigned short* __restrict__ pWl, const float* __restrict__ bl,
    const float* __restrict__ Wlt, const float* __restrict__ rel,
    const unsigned short* __restrict__ pWf2, const float* __restrict__ Wf2t,
    const float* __restrict__ pts,
    const float* __restrict__ Wh, const float* __restrict__ bh,
    const float* __restrict__ bf,
    float* __restrict__ x5, __half* __restrict__ p16, float* __restrict__ q, int ntiles)
{
    __shared__ float xp[4][16*68];
    __shared__ float dd[4][64];
    int lane = threadIdx.x & 63;
    int w = threadIdx.x >> 6;
    int tile = blockIdx.x*4 + w;
    if (tile >= ntiles) return;
    int r0 = tile*16;
    int g4 = (lane >> 4) * 4;
    int rloc = (lane >> 4) * 4;
    int rA = r0 + (lane & 15);
    const float* rowp = c4 + (size_t)lab[rA] * 64;
    bf16x8 ah0, al0, ah1, al1;
    a_frag(rowp, 0, g4, ah0, al0);
    a_frag(rowp, 1, g4, ah1, al1);
    f32x4 acc[4];
    mm64(ah0, al0, ah1, al1, pWl, lane, acc);
#pragma unroll
    for (int nt = 0; nt < 4; ++nt) {
        int c = nt*16 + (lane & 15);
        float bc = bl[c];
        float w0t = Wlt[0*64+c], w1t = Wlt[1*64+c], w2t = Wlt[2*64+c];
#pragma unroll
        for (int reg = 0; reg < 4; ++reg) {
            int r = r0 + rloc + reg;
            float v = acc[nt][reg] + bc + rel[r*3+0]*w0t + rel[r*3+1]*w1t + rel[r*3+2]*w2t;
            v = fmaxf(v, 0.f);
            x5[(size_t)r*64 + c] = v;
            xp[w][(rloc+reg)*68 + c] = v;
        }
    }
    {
        int rowl = lane & 15;
        int jj = lane >> 4;
        int j = jj < 3 ? jj : 2;
        float accd = 0.f;
#pragma unroll 16
        for (int k = 0; k < 64; ++k)
            accd = fmaf(xp[w][rowl*68 + k], Wh[k*3 + j], accd);
        dd[w][rowl*4 + jj] = tanhf(accd + bh[j]);
    }
    const float* lrow = &xp[w][(lane & 15)*68];
    a_frag(lrow, 0, g4, ah0, al0);
    a_frag(lrow, 1, g4, ah1, al1);
    mm64(ah0, al0, ah1, al1, pWf2, lane, acc);
#pragma unroll
    for (int nt = 0; nt < 4; ++nt) {
        int c = nt*16 + (lane & 15);
        float w0t = Wf2t[0*64+c], w1t = Wf2t[1*64+c], w2t = Wf2t[2*64+c];
        float bfc = bf[c];
#pragma unroll
        for (int reg = 0; reg < 4; ++reg) {
            int r = r0 + rloc + reg;
            int rl = rloc + reg;
            float p0 = pts[r*3+0], p1 = pts[r*3+1], p2 = pts[r*3+2];
            float v = acc[nt][reg] + p0*w0t + p1*w1t + p2*w2t;
            p16[(size_t)r*64 + c] = __float2half(v);
            float d0 = dd[w][rl*4+0], d1 = dd[w][rl*4+1], d2 = dd[w][rl*4+2];
            q[(size_t)r*64 + c] = (d0-p0)*w0t + (d1-p1)*w1t + (d2-p2)*w2t + bfc;
        }
    }
}

__global__ __launch_bounds__(256) void k_gemm_final(
    const float* __restrict__ agg, const unsigned short* __restrict__ pWg2,
    const float* __restrict__ bg2,
    const float* __restrict__ x5, const float* __restrict__ x2,
    const unsigned short* __restrict__ pW1, const float* __restrict__ b1,
    const float* __restrict__ W2, const float* __restrict__ b2,
    float* __restrict__ out, int ntiles)
{
    __shared__ float xp[4][16*68];
    int lane = threadIdx.x & 63;
    int w = threadIdx.x >> 6;
    int tile = blockIdx.x*4 + w;
    if (tile >= ntiles) return;
    int r0 = tile*16;
    int g4 = (lane >> 4) * 4;
    int rloc = (lane >> 4) * 4;
    const float* rowp = agg + (size_t)(r0 + (lane & 15)) * 64;
    bf16x8 ah0, al0, ah1, al1;
    a_frag(rowp, 0, g4, ah0, al0);
    a_frag(rowp, 1, g4, ah1, al1);
    f32x4 acc[4];
    mm64(ah0, al0, ah1, al1, pWg2, lane, acc);
#pragma unroll
    for (int nt = 0; nt < 4; ++nt) {
        int c = nt*16 + (lane & 15);
        float bc = bg2[c];
#pragma unroll
        for (int reg = 0; reg < 4; ++reg) {
            int r = r0 + rloc + reg;
            float v = fmaxf(acc[nt][reg] + bc, 0.f)
                    + x5[(size_t)r*64 + c] + x2[(size_t)r*64 + c];
            xp[w][(rloc+reg)*68 + c] = v;
        }
    }
    const float* lrow = &xp[w][(lane & 15)*68];
    a_frag(lrow, 0, g4, ah0, al0);
    a_frag(lrow, 1, g4, ah1, al1);
    mm64(ah0, al0, ah1, al1, pW1, lane, acc);
    float part0[4] = {0.f,0.f,0.f,0.f};
    float part1[4] = {0.f,0.f,0.f,0.f};
    float part2[4] = {0.f,0.f,0.f,0.f};
    float part3[4] = {0.f,0.f,0.f,0.f};
#pragma unroll
    for (int nt = 0; nt < 4; ++nt) {
        int c = nt*16 + (lane & 15);
        float bc = b1[c];
        float4 w2v = *(const float4*)(W2 + c*4);
#pragma unroll
        for (int reg = 0; reg < 4; ++reg) {
            float t = fmaxf(acc[nt][reg] + bc, 0.f);
            part0[reg] = fmaf(t, w2v.x, part0[reg]);
            part1[reg] = fmaf(t, w2v.y, part1[reg]);
            part2[reg] = fmaf(t, w2v.z, part2[reg]);
            part3[reg] = fmaf(t, w2v.w, part3[reg]);
        }
    }
#pragma unroll
    for (int m = 1; m < 16; m <<= 1) {
#pragma unroll
        for (int reg = 0; reg < 4; ++reg) {
            part0[reg] += __shfl_xor(part0[reg], m);
            part1[reg] += __shfl_xor(part1[reg], m);
            part2[reg] += __shfl_xor(part2[reg], m);
            part3[reg] += __shfl_xor(part3[reg], m);
        }
    }
    if ((lane & 15) == 0) {
        float b20 = b2[0], b21 = b2[1], b22 = b2[2], b23 = b2[3];
#pragma unroll
        for (int reg = 0; reg < 4; ++reg) {
            int r = r0 + rloc + reg;
            *(float4*)(out + (size_t)r*4) =
                make_float4(part0[reg]+b20, part1[reg]+b21, part2[reg]+b22, part3[reg]+b23);
        }
    }
}

// ================= segmax (fp16 p, uint2-wide: 4 rows / instruction) ============
// Monotone RNE rounding => max of fp16(p) == fp16(max p): exact-max semantics.

__global__ __launch_bounds__(256) void k_seg_max_gnn(
    const int* __restrict__ rs, const int* __restrict__ srcs,
    const __half* __restrict__ p, float* __restrict__ q, int n)
{
    int lane = threadIdx.x & 63;
    int qd = lane >> 4;        // quarter 0..3 -> 4 srcs per instruction
    int cl = lane & 15;        // 16 lanes cover one 128B row (8B each)
    int wid  = blockIdx.x * (blockDim.x >> 6) + (threadIdx.x >> 6);
    int nw   = gridDim.x * (blockDim.x >> 6);
    const uint2* p4 = (const uint2*)p;      // row = 16 uint2
    for (int d = wid; d < n; d += nw) {
        int du = __builtin_amdgcn_readfirstlane(d);
        int beg = rs[du], end = rs[du+1];
        float4 A0 = make_float4(-1e30f,-1e30f,-1e30f,-1e30f);
        float4 A1 = A0, A2 = A0, A3 = A0;
#define MAXU(A, U) { \
        __half2 h0 = *(__half2*)&(U).x; __half2 h1 = *(__half2*)&(U).y; \
        float2 f0 = __half22float2(h0), f1 = __half22float2(h1); \
        A.x = fmaxf(A.x, f0.x); A.y = fmaxf(A.y, f0.y); \
        A.z = fmaxf(A.z, f1.x); A.w = fmaxf(A.w, f1.y); }
        int c = beg;
        while (c + 16 <= end) {
            int s0 = srcs[c + qd],      s1 = srcs[c + 4 + qd];
            int s2 = srcs[c + 8 + qd],  s3 = srcs[c + 12 + qd];
            uint2 u0 = p4[(size_t)s0*16 + cl];
            uint2 u1 = p4[(size_t)s1*16 + cl];
            uint2 u2 = p4[(size_t)s2*16 + cl];
            uint2 u3 = p4[(size_t)s3*16 + cl];
            MAXU(A0, u0) MAXU(A1, u1) MAXU(A2, u2) MAXU(A3, u3)
            c += 16;
        }
        while (c + 4 <= end) {
            int s0 = srcs[c + qd];
            uint2 u0 = p4[(size_t)s0*16 + cl];
            MAXU(A0, u0)
            c += 4;
        }
        if (c + qd < end) {
            int s0 = srcs[c + qd];
            uint2 u0 = p4[(size_t)s0*16 + cl];
            MAXU(A1, u0)
        }
#undef MAXU
        float4 m;
        m.x = fmaxf(fmaxf(A0.x, A1.x), fmaxf(A2.x, A3.x));
        m.y = fmaxf(fmaxf(A0.y, A1.y), fmaxf(A2.y, A3.y));
        m.z = fmaxf(fmaxf(A0.z, A1.z), fmaxf(A2.z, A3.z));
        m.w = fmaxf(fmaxf(A0.w, A1.w), fmaxf(A2.w, A3.w));
        m.x = fmaxf(m.x, __shfl_xor(m.x, 16)); m.x = fmaxf(m.x, __shfl_xor(m.x, 32));
        m.y = fmaxf(m.y, __shfl_xor(m.y, 16)); m.y = fmaxf(m.y, __shfl_xor(m.y, 32));
        m.z = fmaxf(m.z, __shfl_xor(m.z, 16)); m.z = fmaxf(m.z, __shfl_xor(m.z, 32));
        m.w = fmaxf(m.w, __shfl_xor(m.w, 16)); m.w = fmaxf(m.w, __shfl_xor(m.w, 32));
        if (qd == 0) {
            float4* q4 = (float4*)q;
            size_t o = (size_t)du*16 + cl;
            float4 qv = q4[o];
            q4[o] = make_float4(fmaxf(m.x + qv.x, 0.f), fmaxf(m.y + qv.y, 0.f),
                                fmaxf(m.z + qv.z, 0.f), fmaxf(m.w + qv.w, 0.f));
        }
    }
}

__global__ __launch_bounds__(256, 2) void k_seglab_pre1(
    const int* __restrict__ rsL, const int* __restrict__ srcsL,
    const float* __restrict__ h, const float* __restrict__ pos,
    const float* __restrict__ Wh, const float* __restrict__ bh,
    const float* __restrict__ Wf, const float* __restrict__ bf,
    float* __restrict__ c, __half* __restrict__ pa, float* __restrict__ qa, int m)
{
    int lane = threadIdx.x & 63;
    int wid  = blockIdx.x * (blockDim.x >> 6) + (threadIdx.x >> 6);
    int nw   = gridDim.x * (blockDim.x >> 6);
    REPD(WLOAD, wc, Wf + 3*64)
    float w0 = Wf[0*64+lane], w1 = Wf[1*64+lane], w2 = Wf[2*64+lane];
    float bfl = bf[lane];
    float wh0 = Wh[lane*3+0], wh1 = Wh[lane*3+1], wh2 = Wh[lane*3+2];
    float bh0 = bh[0], bh1 = bh[1], bh2 = bh[2];
    for (int d0 = wid*2; d0 < m; d0 += nw*2) {
        int dA = __builtin_amdgcn_readfirstlane(d0);
        int dB = dA + 1;
        int begA = rsL[dA], endA = rsL[dA+1], endB = rsL[dA+2];
        int ca = begA, cb = endA;
        float aA0=-1e30f, aA1=-1e30f, aB0=-1e30f, aB1=-1e30f;
        while (ca+2 <= endA && cb+2 <= endB) {
            int s0=srcsL[ca], s1=srcsL[ca+1], s2=srcsL[cb], s3=srcsL[cb+1];
            aA0 = fmaxf(aA0, h[(size_t)s0*64+lane]);
            aA1 = fmaxf(aA1, h[(size_t)s1*64+lane]);
            aB0 = fmaxf(aB0, h[(size_t)s2*64+lane]);
            aB1 = fmaxf(aB1, h[(size_t)s3*64+lane]);
            ca += 2; cb += 2;
        }
        while (ca+2 <= endA) {
            int s0=srcsL[ca], s1=srcsL[ca+1];
            aA0 = fmaxf(aA0, h[(size_t)s0*64+lane]);
            aA1 = fmaxf(aA1, h[(size_t)s1*64+lane]);
            ca += 2;
        }
        while (cb+2 <= endB) {
            int s2=srcsL[cb], s3=srcsL[cb+1];
            aB0 = fmaxf(aB0, h[(size_t)s2*64+lane]);
            aB1 = fmaxf(aB1, h[(size_t)s3*64+lane]);
            cb += 2;
        }
        if (ca < endA) aA0 = fmaxf(aA0, h[(size_t)srcsL[ca]*64+lane]);
        if (cb < endB) aB0 = fmaxf(aB0, h[(size_t)srcsL[cb]*64+lane]);
        float cvA = fmaxf(fmaxf(aA0,aA1), 0.f);
        float cvB = fmaxf(fmaxf(aB0,aB1), 0.f);
        c[(size_t)dA*64+lane] = cvA;
        c[(size_t)dB*64+lane] = cvB;
        float d0A = cvA*wh0, d1A = cvA*wh1, d2A = cvA*wh2;
        float d0B = cvB*wh0, d1B = cvB*wh1, d2B = cvB*wh2;
#pragma unroll
        for (int o = 32; o; o >>= 1) {
            d0A += __shfl_xor(d0A,o); d1A += __shfl_xor(d1A,o); d2A += __shfl_xor(d2A,o);
            d0B += __shfl_xor(d0B,o); d1B += __shfl_xor(d1B,o); d2B += __shfl_xor(d2B,o);
        }
        d0A = tanhf(d0A+bh0); d1A = tanhf(d1A+bh1); d2A = tanhf(d2A+bh2);
        d0B = tanhf(d0B+bh0); d1B = tanhf(d1B+bh1); d2B = tanhf(d2B+bh2);
        float pA0 = pos[dA*3+0], pA1 = pos[dA*3+1], pA2 = pos[dA*3+2];
        float pB0 = pos[dB*3+0], pB1 = pos[dB*3+1], pB2 = pos[dB*3+2];
        float s0A=0.f, s1A=0.f, s0B=0.f, s1B=0.f;
        REPP(WFMA, wc, cvA, s0A, s1A)
        REPP(WFMA, wc, cvB, s0B, s1B)
        pa[(size_t)dA*64+lane] = __float2half(s0A+s1A + pA0*w0 + pA1*w1 + pA2*w2);
        pa[(size_t)dB*64+lane] = __float2half(s0B+s1B + pB0*w0 + pB1*w1 + pB2*w2);
        qa[(size_t)dA*64+lane] = (d0A-pA0)*w0 + (d1A-pA1)*w1 + (d2A-pA2)*w2 + bfl;
        qa[(size_t)dB*64+lane] = (d0B-pB0)*w0 + (d1B-pB1)*w1 + (d2B-pB2)*w2 + bfl;
    }
}

__global__ __launch_bounds__(256, 2) void k_gnn_post(
    const float* __restrict__ agg, const float* __restrict__ Wg,
    const float* __restrict__ bg, const float* __restrict__ xres,
    float* __restrict__ out, int n)
{
    int lane = threadIdx.x & 63;
    int wid  = blockIdx.x * (blockDim.x >> 6) + (threadIdx.x >> 6);
    int nw   = gridDim.x * (blockDim.x >> 6);
    REPD(WLOAD, wg, Wg)
    float bgl = bg[lane];
    for (int i0 = wid*2; i0 < n; i0 += nw*2) {
        int iA = __builtin_amdgcn_readfirstlane(i0);
        size_t oA = (size_t)iA*64 + lane, oB = oA + 64;
        float avA = agg[oA], avB = agg[oB];
        float s0A=0.f, s1A=0.f, s0B=0.f, s1B=0.f;
        REPP(WFMA, wg, avA, s0A, s1A)
        REPP(WFMA, wg, avB, s0B, s1B)
        out[oA] = fmaxf(s0A+s1A + bgl, 0.f) + xres[oA];
        out[oB] = fmaxf(s0B+s1B + bgl, 0.f) + xres[oB];
    }
}

// ---------------- launch ----------------

extern "C" void kernel_launch(void* const* d_in, const int* in_sizes, int n_in,
                              void* d_out, int out_size, void* d_ws, size_t ws_size,
                              hipStream_t stream)
{
    const int N = 100000, M = 10000, E0 = 1600000, E1 = 320000;
    const int NB0 = (N + 255) / 256;
    const int NB1 = (M + 255) / 256;
    const int NBL = (M + 255) / 256;
    const int GB0 = (E0 + EPB - 1) / EPB;
    const int GB1 = (E1 + EPB - 1) / EPB;
    const int GBL = (N + EPB - 1) / EPB;

    const float* feat = (const float*)d_in[0];
    const float* pts  = (const float*)d_in[1];
    const float* ctr  = (const float*)d_in[2];
    const int*   lab  = (const int*)d_in[3];
    const int2*  e0   = (const int2*)d_in[4];
    const int2*  e1   = (const int2*)d_in[5];
    const float* feW  = (const float*)d_in[6];
    const float* feb  = (const float*)d_in[7];
    const float* Wh   = (const float*)d_in[8];
    const float* bh   = (const float*)d_in[9];
    const float* Wf   = (const float*)d_in[10];
    const float* bf   = (const float*)d_in[11];
    const float* Wg   = (const float*)d_in[12];
    const float* bg   = (const float*)d_in[13];
    const float* m2lW = (const float*)d_in[14];
    const float* m2lb = (const float*)d_in[15];
    const float* l2mW = (const float*)d_in[16];
    const float* l2mb = (const float*)d_in[17];
    const float* cW1  = (const float*)d_in[18];
    const float* cb1  = (const float*)d_in[19];
    const float* cW2  = (const float*)d_in[20];
    const float* cb2  = (const float*)d_in[21];
    float* out = (float*)d_out;

    char* ws = (char*)d_ws;
    size_t off = 0;
    auto alloc = [&](size_t bytes) -> char* {
        char* r = ws + off; off += (bytes + 255) & ~(size_t)255; return r;
    };
    float*  rel  = (float*)alloc((size_t)N*3*4);
    float*  x1   = (float*)alloc((size_t)N*64*4);
    float*  x2   = (float*)alloc((size_t)N*64*4);   // hosts ebufs pre-compute
    float*  p    = (float*)alloc((size_t)N*64*4);   // h (fp32 label-segmax input)
    float*  q    = (float*)alloc((size_t)N*64*4);
    __half* p16  = (__half*)alloc((size_t)N*64*2);  // fp16 gather buffer
    float*  c    = (float*)alloc((size_t)M*64*4);
    float*  c4   = (float*)alloc((size_t)M*64*4);
    int* rs0     = (int*)alloc((size_t)(N+2)*4);
    int* srcs0   = (int*)alloc((size_t)E0*4);
    int* rs1     = (int*)alloc((size_t)(M+2)*4);
    int* srcs1   = (int*)alloc((size_t)E1*4);
    int* rsL     = (int*)alloc((size_t)(M+2)*4);
    int* srcsL   = (int*)alloc((size_t)N*4);
    int* cnt0    = (int*)alloc((size_t)NB0*4);
    int* cnt1    = (int*)alloc((size_t)NB1*4);
    int* cntL    = (int*)alloc((size_t)NBL*4);
    int* base0   = (int*)alloc((size_t)(NB0+1)*4);
    int* base1   = (int*)alloc((size_t)(NB1+1)*4);
    int* baseL   = (int*)alloc((size_t)(NBL+1)*4);
    int* cur0    = (int*)alloc((size_t)NB0*4);
    int* cur1    = (int*)alloc((size_t)NB1*4);
    int* curL    = (int*)alloc((size_t)NBL*4);
    unsigned short* pWf0  = (unsigned short*)alloc(8192*2);
    unsigned short* pWg0  = (unsigned short*)alloc(8192*2);
    unsigned short* pWm   = (unsigned short*)alloc(8192*2);
    unsigned short* pWl2m = (unsigned short*)alloc(8192*2);
    unsigned short* pWf2  = (unsigned short*)alloc(8192*2);
    unsigned short* pWg2  = (unsigned short*)alloc(8192*2);
    unsigned short* pW1   = (unsigned short*)alloc(8192*2);
    (void)ws_size; (void)in_sizes; (void)n_in; (void)out_size;

    int2* ebuf0 = (int2*)x2;
    int2* ebuf1 = ebuf0 + E0;
    int2* ebufL = ebuf1 + E1;

    dim3 blk(256);
    const int gridM = 640, gSeg = 2048;
    const int NT = N / 16;
    const int gG = (NT + 3) / 4;

    // ---- zero (separate launch: MUST complete before k_prep's hist atomics) ----
    k_zero3<<<1, blk, 0, stream>>>(cnt0, NB0, cnt1, NB1, cntL, NBL);
    // ---- merged pack (7 blocks) + hist (1536 blocks) ----
    k_prep<<<7 + 1536, blk, 0, stream>>>(
        Wf + 0*67*64 + 3*64, pWf0,
        Wg + 0*64*64,        pWg0,
        m2lW,                pWm,
        l2mW,                pWl2m,
        Wf + 2*67*64 + 3*64, pWf2,
        Wg + 2*64*64,        pWg2,
        cW1,                 pW1,
        cnt0, NB0, cnt1, NB1, cntL, NBL,
        e0, E0, e1, E1, lab, N);
    k_bscan3<<<3, 512, 0, stream>>>(cnt0, base0, cur0, NB0, E0,
                                    cnt1, base1, cur1, NB1, E1,
                                    cntL, baseL, curL, NBL, N);
    k_bucket3<<<GB0 + GB1 + GBL, BKT, 0, stream>>>(
        e0, cur0, ebuf0, E0, NB0, GB0,
        e1, cur1, ebuf1, E1, NB1, GB1,
        lab, curL, ebufL, N, NBL);
    k_final3<<<NB0 + NB1 + NBL, 512, 0, stream>>>(
        ebuf0, base0, rs0, srcs0, N, E0, NB0,
        ebuf1, base1, rs1, srcs1, M, E1, NB1,
        ebufL, baseL, rsL, srcsL, M, N, NBL);

    // ---- layer 0 ----
    k_feat_pre0_g<<<gG, blk, 0, stream>>>(feat, pts, ctr, lab, feW, feb,
                                          Wh+0*64*3, bh+0*3,
                                          pWf0, Wf+0*67*64, bf+0*64,
                                          rel, x1, p16, q, NT);
    k_seg_max_gnn<<<gSeg, blk, 0, stream>>>(rs0, srcs0, p16, q, N);
    k_post_m2l_g<<<gG, blk, 0, stream>>>(q, pWg0, bg+0*64, x1,
                                         pWm, m2lb, m2lW+64*64, rel,
                                         x2, p, NT);                        // h -> p (fp32)

    // ---- layer 1 (clusters, VALU) ----
    float* q1 = q + (size_t)M*64;
    k_seglab_pre1<<<gridM, blk, 0, stream>>>(rsL, srcsL, p, ctr,
                                             Wh+1*64*3, bh+1*3, Wf+1*67*64, bf+1*64,
                                             c, p16, q1, M);               // pa -> p16
    k_seg_max_gnn<<<640, blk, 0, stream>>>(rs1, srcs1, p16, q1, M);
    k_gnn_post<<<gridM, blk, 0, stream>>>(q1, Wg+1*64*64, bg+1*64, c, c4, M);

    // ---- l2m (+q fold) + layer 2 + classifier ----
    k_l2m_pre2_g<<<gG, blk, 0, stream>>>(c4, lab, pWl2m, l2mb, l2mW+64*64, rel,
                                         pWf2, Wf+2*67*64, pts,
                                         Wh+2*64*3, bh+2*3, bf+2*64,
                                         x1, p16, q, NT);                   // x5 -> x1
    k_seg_max_gnn<<<gSeg, blk, 0, stream>>>(rs0, srcs0, p16, q, N);
    k_gemm_final<<<gG, blk, 0, stream>>>(q, pWg2, bg+2*64, x1, x2,
                                         pW1, cb1, cW2, cb2, out, NT);
}